// Round 7
// baseline (432.554 us; speedup 1.0000x reference)
//
#include <hip/hip_runtime.h>
#include <math.h>

#define H 32
#define N0 4096
#define EMAX 131072
#define APSTR (4096 * 32)

typedef __attribute__((ext_vector_type(4))) float floatx4;
typedef __attribute__((ext_vector_type(8))) short short8;

__device__ __forceinline__ unsigned short f2bf_bits(float v) {
    union { float f; unsigned u; } c;
    c.f = v;
    unsigned lsb = (c.u >> 16) & 1u;
    c.u += 0x7fffu + lsb;   // RNE; inputs here are small exact integers
    return (unsigned short)(c.u >> 16);
}

__device__ __forceinline__ float bf2f(unsigned short u) {
    union { unsigned x; float f; } c;
    c.x = (unsigned)u << 16;
    return c.f;
}

__device__ __forceinline__ float cvtA(float f) { return f; }
__device__ __forceinline__ float cvtA(unsigned short u) { return bf2f(u); }

// ---------------- sentinel ----------------
__global__ void fill_sentinel_kernel(float* out, int n) {
    int t = blockIdx.x * 256 + threadIdx.x;
    if (t < n) out[t] = 9.0f;
}

// ---------------- CSR build ----------------
__global__ void build_stats_kernel(const int* __restrict__ ei, int E, int* __restrict__ rowcnt,
                                   int* __restrict__ rowcntD, int* __restrict__ diagcnt) {
    int t = blockIdx.x * 256 + threadIdx.x;
    if (t >= E) return;
    int s = ei[t], d = ei[E + t];
    if ((unsigned)s >= N0 || (unsigned)d >= N0) return;
    atomicAdd(&rowcnt[s], 1);
    atomicAdd(&rowcntD[d], 1);
    if (s == d) atomicAdd(&diagcnt[s], 1);
}

// both scans in one pass: wave-level shfl scans (2 barriers total, integer-exact)
__global__ __launch_bounds__(1024) void scan2_kernel(const int* __restrict__ cntA, int* __restrict__ rowpA,
                                                     int* __restrict__ curA, const int* __restrict__ cntB,
                                                     int* __restrict__ rowpB, int* __restrict__ curB) {
    __shared__ int wsA[16], wsB[16], weA[16], weB[16];
    int tid = threadIdx.x;
    int lane = tid & 63, wid = tid >> 6;
    int base = tid * 4;
    int lA[4], lB[4];
    int sA = 0, sB = 0;
#pragma unroll
    for (int i = 0; i < 4; i++) { lA[i] = sA; sA += cntA[base + i]; }
#pragma unroll
    for (int i = 0; i < 4; i++) { lB[i] = sB; sB += cntB[base + i]; }
    int iA = sA, iB = sB;
#pragma unroll
    for (int off = 1; off < 64; off <<= 1) {
        int vA = __shfl_up(iA, off);
        int vB = __shfl_up(iB, off);
        if (lane >= off) { iA += vA; iB += vB; }
    }
    if (lane == 63) { wsA[wid] = iA; wsB[wid] = iB; }
    __syncthreads();
    if (tid < 16) {
        int a = wsA[tid], b = wsB[tid];
        int ia = a, ib = b;
#pragma unroll
        for (int off = 1; off < 16; off <<= 1) {
            int va = __shfl_up(ia, off);
            int vb = __shfl_up(ib, off);
            if (tid >= off) { ia += va; ib += vb; }
        }
        weA[tid] = ia - a;
        weB[tid] = ib - b;
    }
    __syncthreads();
    int preA = weA[wid] + iA - sA;
    int preB = weB[wid] + iB - sB;
#pragma unroll
    for (int i = 0; i < 4; i++) {
        int a = preA + lA[i], b = preB + lB[i];
        rowpA[base + i] = a; curA[base + i] = a;
        rowpB[base + i] = b; curB[base + i] = b;
    }
    if (tid == 1023) { rowpA[N0] = preA + sA; rowpB[N0] = preB + sB; }
}

// fused: CSR fill (blocks [0,nf)) + level-0 msg with inline degree finalize (rest)
__global__ void fillcsr_msg0_kernel(const int* __restrict__ ei, int E, int* __restrict__ cursor,
                                    int* __restrict__ cols, int* __restrict__ cursorD,
                                    int* __restrict__ srcs, const float* __restrict__ x,
                                    const float* __restrict__ Wb, const int* __restrict__ rcntD,
                                    const int* __restrict__ diagcnt, float* __restrict__ dis,
                                    float* __restrict__ fixb, float* __restrict__ msg, int n) {
    int nf = (E + 255) >> 8;
    int tid = threadIdx.x;
    if ((int)blockIdx.x < nf) {
        int t = blockIdx.x * 256 + tid;
        if (t >= E) return;
        int s = ei[t], d = ei[E + t];
        if ((unsigned)s >= N0 || (unsigned)d >= N0) return;
        int pos = atomicAdd(&cursor[s], 1);
        cols[pos] = d;
        int posD = atomicAdd(&cursorD[d], 1);
        srcs[posD] = s;
    } else {
        int idx = ((int)blockIdx.x - nf) * 256 + tid;
        if (idx >= n * 32) return;
        int i = idx >> 5, c = idx & 31;
        float fx = diagcnt[i] > 0 ? 0.f : 2.f;
        float dg = (float)rcntD[i] + fx;
        float di = dg > 0.f ? 1.f / sqrtf(dg) : 0.f;
        if (c == 0) { dis[i] = di; fixb[i] = fx; }
        float s = x[i * 3] * Wb[c] + x[i * 3 + 1] * Wb[32 + c] + x[i * 3 + 2] * Wb[64 + c];
        msg[idx] = s * di;
    }
}

// ---------------- level-0 fused augment+pool; A1 written as bf16 (exact small ints) ------
__global__ __launch_bounds__(256) void aug0_kernel(const int* __restrict__ rowp, const int* __restrict__ cols,
                                                   const int* __restrict__ perm, const int* __restrict__ invperm,
                                                   int kOut, int ldC, unsigned short* __restrict__ C) {
    __shared__ float row[2048];
    int a = blockIdx.x;
    int tid = threadIdx.x;
    for (int j = tid; j < ldC; j += 256) row[j] = 0.f;
    __syncthreads();
    if (a < kOut) {
        int pa = perm[a];
        int s0 = rowp[pa], s1 = rowp[pa + 1];
        int sub = tid & 7, grp = tid >> 3;   // 32 edge-lanes x 8 inner-lanes
        for (int e = s0 + grp; e < s1; e += 32) {
            int k = cols[e];
            if (sub == 0) {
                int ip = invperm[k];
                if (ip >= 0) atomicAdd(&row[ip], 2.0f);
            }
            int t1 = rowp[k + 1];
            for (int e2 = rowp[k] + sub; e2 < t1; e2 += 8) {
                int ip2 = invperm[cols[e2]];
                if (ip2 >= 0) atomicAdd(&row[ip2], 1.0f);
            }
        }
    }
    __syncthreads();
    for (int j = tid; j < ldC; j += 256)
        C[(long)a * ldC + j] = (j == a) ? 0 : f2bf_bits(row[j]);
}

// ---------------- deeper levels ----------------
// level 1->2: transpose-only gather (bf16) + zero GcT rows [kOut, ldn) + zero C accumulator.
// (row-gather of the A-operand is fused into mfma_aug's global loads)
__global__ void gatherABt_bf16_kernel(const unsigned short* __restrict__ M, int ldM,
                                      const int* __restrict__ invp, int kOut,
                                      unsigned short* __restrict__ GcT, int ldn,
                                      float* __restrict__ Cz) {
    __shared__ float t[32][33];
    __shared__ int rj[32];
    int tseg = (ldM >> 5) * (ldM >> 5);
    int zrow = (((ldn - kOut) * ldM) + 255) >> 8;
    int u = blockIdx.x;
    int tid = threadIdx.x;
    if (u < tseg) {
        int ntx = ldM >> 5;
        int bx = u % ntx, by = u / ntx;
        int j0 = bx * 32, k0 = by * 32;
        int tx = tid & 31, ty = tid >> 5;
        if (ty == 0) rj[tx] = invp[j0 + tx];
        __syncthreads();
        for (int y = ty; y < 32; y += 8)
            t[y][tx] = bf2f(M[(long)(k0 + y) * ldM + j0 + tx]);   // coalesced read
        __syncthreads();
        for (int y = ty; y < 32; y += 8) {
            int r = rj[y];
            if (r >= 0)
                GcT[(long)r * ldM + k0 + tx] =
                    f2bf_bits(t[tx][y] + ((k0 + tx) == (j0 + y) ? 1.f : 0.f));
        }
    } else if (u < tseg + zrow) {
        int e = (u - tseg) * 256 + tid;
        if (e < (ldn - kOut) * ldM) GcT[(long)kOut * ldM + e] = 0;
    } else {
        int t4 = (u - tseg - zrow) * 256 + tid;
        if (t4 < (ldn * ldn) >> 2) {
            floatx4 z = {0.f, 0.f, 0.f, 0.f};
            ((floatx4*)Cz)[t4] = z;
        }
    }
}

// fp32 levels: transpose-only gather -> GcT[b][k] + zero-rows + zero C + zero deg
__global__ void gatherT_kernel(const float* __restrict__ M, int ldM,
                               const int* __restrict__ invp, int kOut,
                               float* __restrict__ GcT, int ldn,
                               float* __restrict__ Cz, float* __restrict__ deg) {
    __shared__ float t[32][33];
    __shared__ int rj[32];
    int tseg = (ldM >> 5) * (ldM >> 5);
    int zrow = (((ldn - kOut) * ldM) + 255) >> 8;
    int zcseg = ((ldn * ldn) / 4 + 255) / 256;
    int u = blockIdx.x;
    int tid = threadIdx.x;
    if (u < tseg) {
        int ntx = ldM >> 5;
        int bx = u % ntx, by = u / ntx;
        int j0 = bx * 32, k0 = by * 32;
        int tx = tid & 31, ty = tid >> 5;
        if (ty == 0) rj[tx] = invp[j0 + tx];
        __syncthreads();
        for (int y = ty; y < 32; y += 8)
            t[y][tx] = M[(long)(k0 + y) * ldM + j0 + tx];   // coalesced read
        __syncthreads();
        for (int y = ty; y < 32; y += 8) {
            int r = rj[y];
            if (r >= 0)
                GcT[(long)r * ldM + k0 + tx] = t[tx][y] + ((k0 + tx) == (j0 + y) ? 1.f : 0.f);
        }
    } else if (u < tseg + zrow) {
        int e = (u - tseg) * 256 + tid;
        if (e < (ldn - kOut) * ldM) GcT[(long)kOut * ldM + e] = 0.f;
    } else if (u < tseg + zrow + zcseg) {
        int t4 = (u - tseg - zrow) * 256 + tid;
        if (t4 < (ldn * ldn) >> 2) {
            floatx4 z = {0.f, 0.f, 0.f, 0.f};
            ((floatx4*)Cz)[t4] = z;
        }
    } else {
        int tt = (u - tseg - zrow - zcseg) * 256 + tid;
        if (tt < ldn) deg[tt] = 0.f;
    }
}

// MFMA augment GEMM; A-operand row-gathered inline from bf16 A1 (perm + diag-add, zero rows >= kOut)
__global__ __launch_bounds__(256) void mfma_aug_kernel(const unsigned short* __restrict__ A1,
                                                       const int* __restrict__ perm, int kOut,
                                                       const unsigned short* __restrict__ Bop,
                                                       float* __restrict__ C, int K, int ldC, int kchunk) {
    __shared__ __align__(16) unsigned short lA[64 * 32];
    __shared__ __align__(16) unsigned short lB[64 * 32];
    const int tid = threadIdx.x;
    const int lane = tid & 63;
    const int w = tid >> 6;
    const int a0 = blockIdx.y * 64, b0 = blockIdx.x * 64;
    const int kbase = blockIdx.z * kchunk;
    const int r0 = tid >> 2;
    const int c8 = (tid & 3) * 8;
    const int arow = a0 + r0;
    const int pa = (arow < kOut) ? perm[arow] : -1;
    const unsigned short* gA = A1 + (pa >= 0 ? (long)pa * K : 0) + kbase + c8;
    const unsigned short* gB = Bop + (long)(b0 + r0) * K + kbase + c8;
    const int wm = (w & 1) * 32;
    const int wn = (w >> 1) * 32;
    const int lm = lane & 15;
    const int quad = lane >> 4;
    floatx4 acc[2][2];
#pragma unroll
    for (int i = 0; i < 2; i++)
#pragma unroll
        for (int j = 0; j < 2; j++) {
            floatx4 z = {0.f, 0.f, 0.f, 0.f};
            acc[i][j] = z;
        }
    for (int k0 = 0; k0 < kchunk; k0 += 32) {
        short8 va;
        if (pa >= 0) {
            va = *(const short8*)(gA + k0);
            int cb = kbase + c8 + k0;
            if (pa >= cb && pa < cb + 8) {
                int e = pa - cb;
                va[e] = (short)f2bf_bits(bf2f((unsigned short)va[e]) + 1.0f);
            }
        } else {
            short8 z = {0, 0, 0, 0, 0, 0, 0, 0};
            va = z;
        }
        short8 vb = *(const short8*)(gB + k0);
        __syncthreads();
        *(short8*)&lA[r0 * 32 + c8] = va;
        *(short8*)&lB[r0 * 32 + c8] = vb;
        __syncthreads();
        short8 af[2], bf[2];
#pragma unroll
        for (int mi = 0; mi < 2; mi++) af[mi] = *(const short8*)&lA[(wm + mi * 16 + lm) * 32 + quad * 8];
#pragma unroll
        for (int ni = 0; ni < 2; ni++) bf[ni] = *(const short8*)&lB[(wn + ni * 16 + lm) * 32 + quad * 8];
#pragma unroll
        for (int mi = 0; mi < 2; mi++)
#pragma unroll
            for (int ni = 0; ni < 2; ni++)
                acc[mi][ni] = __builtin_amdgcn_mfma_f32_16x16x32_bf16(af[mi], bf[ni], acc[mi][ni], 0, 0, 0);
    }
#pragma unroll
    for (int mi = 0; mi < 2; mi++)
#pragma unroll
        for (int ni = 0; ni < 2; ni++) {
            int col = b0 + wn + ni * 16 + lm;
#pragma unroll
            for (int r = 0; r < 4; r++) {
                int row = a0 + wm + mi * 16 + quad * 4 + r;
                if (row != col) atomicAdd(&C[(long)row * ldC + col], acc[mi][ni][r]);
            }
        }
}

// fp32 GEMM: A-operand row-gathered inline (perm + diag), B from GcT[b][K];
// atomic accumulate into pre-zeroed C (exact ints, order-free); block-reduced colsum -> deg.
__global__ __launch_bounds__(256) void gemm64_atomic_kernel(const float* __restrict__ A,
                                                            const int* __restrict__ perm, int kOut,
                                                            const float* __restrict__ GcT,
                                                            float* __restrict__ C, float* __restrict__ deg,
                                                            int K, int ldC, int kchunk) {
    __shared__ float As[32][68];
    __shared__ float Bs[32][68];
    const int tid = threadIdx.x;
    const int a0 = blockIdx.y * 64, b0 = blockIdx.x * 64;
    const int kbase = blockIdx.z * kchunk;
    const int tx = tid & 15, ty = tid >> 4;
    const int lr = tid >> 2;
    const int lk = (tid & 3) * 8;
    const int arow = a0 + lr;
    const int pa = (arow < kOut) ? perm[arow] : -1;
    const float* gA = A + (pa >= 0 ? (long)pa * K : 0) + lk + kbase;
    const float* gB = GcT + (long)(b0 + lr) * K + lk + kbase;
    float acc[4][4];
#pragma unroll
    for (int i = 0; i < 4; i++)
#pragma unroll
        for (int j = 0; j < 4; j++) acc[i][j] = 0.f;
    for (int k0 = 0; k0 < kchunk; k0 += 32) {
        float a8[8], b8[8];
        if (pa >= 0) {
#pragma unroll
            for (int i = 0; i < 8; i++) a8[i] = gA[k0 + i];
            int cb = kbase + lk + k0;
            if (pa >= cb && pa < cb + 8) a8[pa - cb] += 1.f;
        } else {
#pragma unroll
            for (int i = 0; i < 8; i++) a8[i] = 0.f;
        }
#pragma unroll
        for (int i = 0; i < 8; i++) b8[i] = gB[k0 + i];
        __syncthreads();
#pragma unroll
        for (int i = 0; i < 8; i++) As[lk + i][lr] = a8[i];
#pragma unroll
        for (int i = 0; i < 8; i++) Bs[lk + i][lr] = b8[i];
        __syncthreads();
#pragma unroll
        for (int k = 0; k < 32; k++) {
            floatx4 av = *(const floatx4*)&As[k][ty * 4];
            floatx4 bv = *(const floatx4*)&Bs[k][tx * 4];
#pragma unroll
            for (int i = 0; i < 4; i++)
#pragma unroll
                for (int j = 0; j < 4; j++) acc[i][j] += av[i] * bv[j];
        }
    }
    __syncthreads();                       // As free for reuse as column-partial buffer
    float* cps = &As[0][0];                // [16][68]
    float cloc[4] = {0.f, 0.f, 0.f, 0.f};
#pragma unroll
    for (int i = 0; i < 4; i++)
#pragma unroll
        for (int j = 0; j < 4; j++) {
            int a = a0 + ty * 4 + i, b = b0 + tx * 4 + j;
            float v = acc[i][j];
            if (a != b) {
                if (v != 0.f) atomicAdd(&C[(long)a * ldC + b], v);
                cloc[j] += v;
            }
        }
#pragma unroll
    for (int j = 0; j < 4; j++) cps[ty * 68 + tx * 4 + j] = cloc[j];
    __syncthreads();
    if (tid < 64) {
        float s = 0.f;
        for (int t = 0; t < 16; t++) s += cps[t * 68 + tid];
        if (s != 0.f) atomicAdd(&deg[b0 + tid], s);
    }
}

// ---------------- K1: colsum partials (optional) || raw msg (no dis scaling) ----------------
template <typename AT>
__global__ void colsum_rawmsg_kernel(const AT* __restrict__ A, int ld, int hascs,
                                     const float* __restrict__ x, const int* __restrict__ perm,
                                     const float* __restrict__ vals, const float* __restrict__ xup,
                                     const int* __restrict__ invp, const float* __restrict__ Wb,
                                     float* __restrict__ degp, float* __restrict__ rm, int n) {
    int nc = hascs ? (ld >> 8) * (ld >> 6) : 0;
    int tid = threadIdx.x;
    if ((int)blockIdx.x < nc) {
        int gx = ld >> 8;
        int bi = blockIdx.x % gx, jb = blockIdx.x / gx;
        int i = bi * 256 + tid;
        int j0 = jb * 64;
        const AT* p = A + (long)j0 * ld + i;
        float s0 = 0.f, s1 = 0.f, s2 = 0.f, s3 = 0.f, s4 = 0.f, s5 = 0.f, s6 = 0.f, s7 = 0.f;
#pragma unroll
        for (int jq = 0; jq < 64; jq += 8) {
            float v[8];
#pragma unroll
            for (int q = 0; q < 8; q++) v[q] = cvtA(p[(long)(jq + q) * ld]);
            s0 += v[0]; s1 += v[1]; s2 += v[2]; s3 += v[3];
            s4 += v[4]; s5 += v[5]; s6 += v[6]; s7 += v[7];
        }
        float s = ((s0 + s1) + (s2 + s3)) + ((s4 + s5) + (s6 + s7));
        degp[(long)jb * ld + i] = s;
    } else {
        int idx = ((int)blockIdx.x - nc) * 256 + tid;
        if (idx >= ld * 32) return;
        int i = idx >> 5, c = idx & 31;
        float v = 0.f;
        if (i < n) {
            int src = perm ? perm[i] : i;
            float vs = vals ? vals[i] : 1.f;
            int ip = invp ? invp[i] : -1;
            float s = 0.f;
#pragma unroll
            for (int q = 0; q < 32; q++) {
                float xv = x[(long)src * 32 + q];
                if (ip >= 0) xv += xup[(long)ip * 32 + q];
                s += xv * Wb[q * 32 + c];
            }
            v = s * vs;
        }
        rm[idx] = v;
    }
}

// ---------------- aggT with inline dis_j scaling ----------------
template <typename AT>
__global__ __launch_bounds__(256) void aggTs_kernel(const AT* __restrict__ A,
                                                    const float* __restrict__ rm,
                                                    const float* __restrict__ degp, int nparts,
                                                    const float* __restrict__ disC,
                                                    float* __restrict__ aggp, int n, int ld, int jchunk) {
    __shared__ float As[64][64];
    __shared__ float Ms[64][32];
    __shared__ float sdisJ[256];
    const int tid = threadIdx.x;
    const int i0 = blockIdx.x * 64;
    const int j0 = blockIdx.y * jchunk;
    for (int j = tid; j < jchunk; j += 256) {
        int jj = j0 + j;
        float d;
        if (nparts) {
            float s = 0.f;
            for (int z = 0; z < nparts; z++) s += degp[(long)z * ld + jj];
            d = 1.f / sqrtf(s + 2.f);
        } else {
            d = disC[jj];
        }
        sdisJ[j] = d;
    }
    __syncthreads();
    const int il = tid & 63;
    const int cg = tid >> 6;
    const int i = i0 + il;
    const int mrow = tid >> 2;
    const int mc = (tid & 3) * 8;
    float acc[8];
#pragma unroll
    for (int q = 0; q < 8; q++) acc[q] = 0.f;
    for (int jb = j0; jb < j0 + jchunk; jb += 64) {
        AT a16[16];
        float m8[8];
#pragma unroll
        for (int q = 0; q < 16; q++) a16[q] = A[(long)(jb + cg + 4 * q) * ld + i0 + il];
#pragma unroll
        for (int q = 0; q < 8; q++) m8[q] = rm[(long)(jb + mrow) * 32 + mc + q];
        __syncthreads();
#pragma unroll
        for (int q = 0; q < 16; q++) As[cg + 4 * q][il] = cvtA(a16[q]);
        float ds = sdisJ[jb - j0 + mrow];
#pragma unroll
        for (int q = 0; q < 8; q++) Ms[mrow][mc + q] = m8[q] * ds;
        __syncthreads();
#pragma unroll
        for (int jl = 0; jl < 64; jl++) {
            float a = As[jl][il];
#pragma unroll
            for (int q = 0; q < 8; q++) acc[q] += a * Ms[jl][cg * 8 + q];
        }
        __syncthreads();
    }
    if (i < n) {
#pragma unroll
        for (int q = 0; q < 8; q++) aggp[(long)blockIdx.y * APSTR + (long)i * 32 + cg * 8 + q] = acc[q];
    }
}

// ---------------- epilogue: partial sum + dis finalize + self term + keys ----------------
__global__ void epi2_kernel(const float* __restrict__ aggp, int jsplit, const float* __restrict__ rm,
                            const float* __restrict__ degp, int nparts, float* __restrict__ disC,
                            int writeDis, int ld, const float* __restrict__ bb,
                            float* __restrict__ out, int n, const float* __restrict__ p, int npow,
                            unsigned long long* __restrict__ keys) {
    __shared__ float psh[32];
    if (p) {
        if (threadIdx.x < 32) psh[threadIdx.x] = p[threadIdx.x];
        __syncthreads();
    }
    int idx = blockIdx.x * 256 + threadIdx.x;
    int tot = (p ? npow : n) * 32;
    if (idx >= tot) return;
    int i = idx >> 5, c = idx & 31;
    float di;
    if (nparts) {
        float s = 0.f;
        for (int z = 0; z < nparts; z++) s += degp[(long)z * ld + i];
        di = 1.f / sqrtf(s + 2.f);
    } else {
        di = disC[i];
    }
    float v = 0.f;
    if (i < n) {
        float s = 0.f;
        for (int z = 0; z < jsplit; z++) s += aggp[(long)z * APSTR + idx];
        v = (s + 2.f * di * rm[idx]) * di + bb[c];
        v = fmaxf(v, 0.f);
        out[idx] = v;
    }
    if (writeDis && c == 0) disC[i] = di;
    if (p) {
        float pc = psh[c];
        float d = v * pc;
        float nq = pc * pc;
#pragma unroll
        for (int st = 16; st >= 1; st >>= 1) {
            d += __shfl_xor(d, st);
            nq += __shfl_xor(nq, st);
        }
        if (c == 0) {
            unsigned long long kk = 0ULL;
            if (i < n) {
                float sc = tanhf(d / sqrtf(nq));
                unsigned u = __float_as_uint(sc);
                u = (u & 0x80000000u) ? ~u : (u | 0x80000000u);
                kk = ((unsigned long long)u << 32) | (unsigned)(~i);
            }
            keys[i] = kk;
        }
    }
}

// level-0 sparse agg + epilogue + level-0 pooling keys (wave-reduced)
__global__ void cscagg_epi_keys_kernel(const int* __restrict__ rowpD, const int* __restrict__ srcs,
                                       const float* __restrict__ msg, const float* __restrict__ dis,
                                       const float* __restrict__ fixb, const float* __restrict__ bb,
                                       float* __restrict__ out, int n, const float* __restrict__ p,
                                       unsigned long long* __restrict__ keys) {
    __shared__ float psh[32];
    if (threadIdx.x < 32) psh[threadIdx.x] = p[threadIdx.x];
    __syncthreads();
    int idx = blockIdx.x * 256 + threadIdx.x;
    if (idx >= n * 32) return;
    int i = idx >> 5, c = idx & 31;
    float acc = 0.f;
    int e0 = rowpD[i], e1 = rowpD[i + 1];
    for (int e = e0; e < e1; e++) acc += msg[(long)srcs[e] * 32 + c];
    float v = (acc + fixb[i] * msg[idx]) * dis[i] + bb[c];
    v = fmaxf(v, 0.f);
    out[idx] = v;
    float pc = psh[c];
    float d = v * pc;
    float nq = pc * pc;
#pragma unroll
    for (int st = 16; st >= 1; st >>= 1) {
        d += __shfl_xor(d, st);
        nq += __shfl_xor(nq, st);
    }
    if (c == 0) {
        float sc = tanhf(d / sqrtf(nq));
        unsigned u = __float_as_uint(sc);
        u = (u & 0x80000000u) ? ~u : (u | 0x80000000u);
        keys[i] = ((unsigned long long)u << 32) | (unsigned)(~i);
    }
}

// final up-level msg (32->3) with fused unpool
__global__ void msg3up_kernel(const float* __restrict__ res, const float* __restrict__ xup,
                              const int* __restrict__ invp, const float* __restrict__ Wb,
                              const float* __restrict__ dis, float* __restrict__ msg, int n) {
    int idx = blockIdx.x * 256 + threadIdx.x;
    if (idx >= n * 3) return;
    int i = idx / 3, c = idx % 3;
    int ip = invp[i];
    float s = 0.f;
#pragma unroll
    for (int q = 0; q < 32; q++) {
        float xv = res[(long)i * 32 + q];
        if (ip >= 0) xv += xup[(long)ip * 32 + q];
        s += xv * Wb[q * 3 + c];
    }
    msg[idx] = s * dis[i];
}

// final sparse GCN epilogue + log_softmax fused, writes d_out directly
__global__ void cscagg_lsm_kernel(const int* __restrict__ rowpD, const int* __restrict__ srcs,
                                  const float* __restrict__ msg, const float* __restrict__ dis,
                                  const float* __restrict__ fixb, const float* __restrict__ bb,
                                  float* __restrict__ out, int n) {
    int i = blockIdx.x * 256 + threadIdx.x;
    if (i >= n) return;
    float a0 = 0.f, a1 = 0.f, a2 = 0.f;
    int e0 = rowpD[i], e1 = rowpD[i + 1];
    for (int e = e0; e < e1; e++) {
        const float* m = &msg[(long)srcs[e] * 3];
        a0 += m[0]; a1 += m[1]; a2 += m[2];
    }
    float di = dis[i], fx = fixb[i];
    float v0 = (a0 + fx * msg[i * 3]) * di + bb[0];
    float v1 = (a1 + fx * msg[i * 3 + 1]) * di + bb[1];
    float v2 = (a2 + fx * msg[i * 3 + 2]) * di + bb[2];
    float m = fmaxf(v0, fmaxf(v1, v2));
    float s = expf(v0 - m) + expf(v1 - m) + expf(v2 - m);
    float l = m + logf(s);
    out[i * 3] = v0 - l;
    out[i * 3 + 1] = v1 - l;
    out[i * 3 + 2] = v2 - l;
}

// standalone top-k rank
__global__ __launch_bounds__(256) void topk_rank_kernel(const unsigned long long* __restrict__ keys,
                                                        int npow, int k, int* __restrict__ perm,
                                                        float* __restrict__ vals,
                                                        int* __restrict__ invperm) {
    __shared__ unsigned long long ks[4096];
    __shared__ int psum[256];
    const int tid = threadIdx.x;
    for (int t = tid; t < npow; t += 256) ks[t] = keys[t];
    __syncthreads();
    const int m = tid & 15;
    const int chunk = tid >> 4;
    const int myi = blockIdx.x * 16 + m;
    unsigned long long my = ks[myi];
    const int cl = npow >> 4;
    const unsigned long long* base = &ks[chunk * cl];
    int r = 0;
#pragma unroll 4
    for (int j = 0; j < cl; j++) r += (base[j] > my) ? 1 : 0;
    psum[chunk * 16 + m] = r;
    __syncthreads();
    if (tid < 16) {
        int mk_i = blockIdx.x * 16 + tid;
        unsigned long long mk = ks[mk_i];
        int rank = 0;
#pragma unroll
        for (int c = 0; c < 16; c++) rank += psum[c * 16 + tid];
        invperm[mk_i] = (rank < k) ? rank : -1;
        if (rank < k) {
            perm[rank] = (int)(~(unsigned)mk);
            unsigned u = (unsigned)(mk >> 32);
            u = (u & 0x80000000u) ? (u ^ 0x80000000u) : ~u;
            vals[rank] = __uint_as_float(u);
        }
    }
}

// ---------------- host ----------------
static void run_dense(hipStream_t st, const void* A, int abf, int n, int ld, const float* x,
                      const int* perm, const float* vals, const float* xup, const int* invp,
                      const float* Wt, const float* bt, float* out,
                      float* degp, int nparts, int hascs, float* disC, int writeDis,
                      float* aggp, float* rm,
                      const float* pnext, int npow, unsigned long long* keys) {
    {
        int nc = hascs ? (ld >> 8) * (ld >> 6) : 0;
        int g = nc + (ld * 32 + 255) / 256;
        if (abf)
            colsum_rawmsg_kernel<unsigned short><<<g, 256, 0, st>>>(
                (const unsigned short*)A, ld, hascs, x, perm, vals, xup, invp, Wt, degp, rm, n);
        else
            colsum_rawmsg_kernel<float><<<g, 256, 0, st>>>(
                (const float*)A, ld, hascs, x, perm, vals, xup, invp, Wt, degp, rm, n);
    }
    int jsplit = (ld >= 256) ? (ld >> 8) : 1;
    if (jsplit < 1) jsplit = 1;
    int jchunk = ld / jsplit;
    dim3 ga(ld / 64, jsplit);
    if (abf)
        aggTs_kernel<unsigned short><<<ga, 256, 0, st>>>((const unsigned short*)A, rm,
                                                         nparts ? degp : nullptr, nparts, disC,
                                                         aggp, n, ld, jchunk);
    else
        aggTs_kernel<float><<<ga, 256, 0, st>>>((const float*)A, rm, nparts ? degp : nullptr,
                                                nparts, disC, aggp, n, ld, jchunk);
    int gme = ((pnext ? npow : n) * 32 + 255) / 256;
    epi2_kernel<<<gme, 256, 0, st>>>(aggp, jsplit, rm, nparts ? degp : nullptr, nparts, disC,
                                     writeDis, ld, bt, out, n, pnext, npow, keys);
}

extern "C" void kernel_launch(void* const* d_in, const int* in_sizes, int n_in,
                              void* d_out, int out_size, void* d_ws, size_t ws_size,
                              hipStream_t stream) {
    const float* x0f = (const float*)d_in[0];
    const int* eidx = (const int*)d_in[1];
    const float* W0f = (const float*)d_in[2];
    const float* b0f = (const float*)d_in[3];
    const float* Wdf = (const float*)d_in[4];
    const float* bdf = (const float*)d_in[5];
    const float* Pf = (const float*)d_in[6];
    const float* Wuf = (const float*)d_in[7];
    const float* buf2 = (const float*)d_in[8];
    const float* Wlf = (const float*)d_in[9];
    const float* blf = (const float*)d_in[10];
    const int E = in_sizes[1] / 2;

    unsigned char* w = (unsigned char*)d_ws;
    size_t off = 0;
    auto alloc = [&](size_t bytes) -> void* {
        void* p = w + off;
        off += (bytes + 255) & ~(size_t)255;
        return p;
    };
    int* rowcnt = (int*)alloc(N0 * 4);
    int* rowcntD = (int*)alloc(N0 * 4);
    int* diagcnt = (int*)alloc(N0 * 4);
    int* rowp = (int*)alloc((N0 + 1) * 4);
    int* rowpD = (int*)alloc((N0 + 1) * 4);
    int* cursor = (int*)alloc(N0 * 4);
    int* cursorD = (int*)alloc(N0 * 4);
    int* cols = (int*)alloc((size_t)EMAX * 4);
    int* srcs = (int*)alloc((size_t)EMAX * 4);
    float* dis0 = (float*)alloc(N0 * 4);
    float* fixb0 = (float*)alloc(N0 * 4);
    unsigned long long* keys = (unsigned long long*)alloc((size_t)N0 * 8);
    unsigned short* A1 = (unsigned short*)alloc((size_t)2048 * 2048 * 2);   // bf16 exact ints
    float* A2 = (float*)alloc((size_t)1024 * 1024 * 4);
    float* A3 = (float*)alloc((size_t)512 * 512 * 4);
    float* A4 = (float*)alloc((size_t)256 * 256 * 4);
    float* Gc = (float*)alloc((size_t)2048 * 1024 * 4);
    unsigned short* GcTb = (unsigned short*)alloc((size_t)1024 * 2048 * 2);
    float* degp = (float*)alloc((size_t)32 * 2048 * 4);
    float* aggp = (float*)alloc((size_t)8 * APSTR * 4);
    float* xs0 = (float*)alloc((size_t)N0 * H * 4);
    float* xs1 = (float*)alloc((size_t)2000 * H * 4);
    float* xs2 = (float*)alloc((size_t)1000 * H * 4);
    float* xs3 = (float*)alloc((size_t)500 * H * 4);
    float* xtB = (float*)alloc((size_t)N0 * H * 4);
    float* xtC = (float*)alloc((size_t)N0 * H * 4);
    float* msgb = (float*)alloc((size_t)N0 * H * 4);
    float* disL = (float*)alloc((size_t)4 * N0 * 4);
    int* invpermL = (int*)alloc((size_t)4 * N0 * 4);
    const int ksz[4] = {2000, 1000, 500, 250};
    int* perm[4];
    float* vals[4];
    for (int i = 0; i < 4; i++) perm[i] = (int*)alloc((size_t)ksz[i] * 4);
    for (int i = 0; i < 4; i++) vals[i] = (float*)alloc((size_t)ksz[i] * 4);

    if (off > ws_size) {
        fill_sentinel_kernel<<<(out_size + 255) / 256, 256, 0, stream>>>((float*)d_out, out_size);
        return;
    }

    const int nlvl[5] = {N0, 2000, 1000, 500, 250};
    const int ldl[5] = {N0, 2048, 1024, 512, 256};
    const int npw[4] = {4096, 2048, 1024, 512};
    void* Afp[5] = {nullptr, A1, A2, A3, A4};
    const int abfL[5] = {0, 1, 0, 0, 0};
    float* xsb[4] = {xs0, xs1, xs2, xs3};

    // ---- CSR build + level-0 stats ----
    hipMemsetAsync(rowcnt, 0, (size_t)N0 * 3 * 4, stream);
    build_stats_kernel<<<(E + 255) / 256, 256, 0, stream>>>(eidx, E, rowcnt, rowcntD, diagcnt);
    scan2_kernel<<<1, 1024, 0, stream>>>(rowcnt, rowp, cursor, rowcntD, rowpD, cursorD);
    {
        int nf = (E + 255) / 256;
        int nm = (N0 * H + 255) / 256;
        fillcsr_msg0_kernel<<<nf + nm, 256, 0, stream>>>(eidx, E, cursor, cols, cursorD, srcs,
                                                         x0f, W0f, rowcntD, diagcnt, dis0, fixb0,
                                                         msgb, N0);
    }
    cscagg_epi_keys_kernel<<<(N0 * H + 255) / 256, 256, 0, stream>>>(rowpD, srcs, msgb, dis0, fixb0,
                                                                     b0f, xs0, N0, Pf, keys);
    float* xcur = xs0;

    // ---- down path ----
    for (int i = 0; i < 4; ++i) {
        int kk = ksz[i], ldn = ldl[i + 1];
        topk_rank_kernel<<<npw[i] / 16, 256, 0, stream>>>(keys, npw[i], kk, perm[i], vals[i],
                                                          invpermL + i * N0);
        // ---- build A_{i+1} ----
        if (i == 0) {
            aug0_kernel<<<ldn, 256, 0, stream>>>(rowp, cols, perm[0], invpermL, kk, ldn, A1);
        } else if (i == 1) {
            int ldM = ldl[i];
            int tseg = (ldM >> 5) * (ldM >> 5);
            int zrow = (((ldn - kk) * ldM) + 255) >> 8;
            int zseg = ((ldn * ldn) / 4 + 255) / 256;
            gatherABt_bf16_kernel<<<tseg + zrow + zseg, 256, 0, stream>>>(
                A1, ldM, invpermL + i * N0, kk, GcTb, ldn, A2);
            int ksplit = 2;
            int kchunk = ldM / ksplit;
            dim3 gg(ldn / 64, ldn / 64, ksplit);
            mfma_aug_kernel<<<gg, 256, 0, stream>>>(A1, perm[i], kk, GcTb, A2, ldM, ldn, kchunk);
        } else {
            int ldM = ldl[i];
            int tseg = (ldM >> 5) * (ldM >> 5);
            int zrow = (((ldn - kk) * ldM) + 255) >> 8;
            int zcseg = ((ldn * ldn) / 4 + 255) / 256;
            int dseg = (ldn + 255) / 256;
            gatherT_kernel<<<tseg + zrow + zcseg + dseg, 256, 0, stream>>>(
                (const float*)Afp[i], ldM, invpermL + i * N0, kk, Gc, ldn,
                (float*)Afp[i + 1], degp);
            int ksplit = 8;
            int kchunk = ldM / ksplit;
            dim3 gg(ldn / 64, ldn / 64, ksplit);
            gemm64_atomic_kernel<<<gg, 256, 0, stream>>>((const float*)Afp[i], perm[i], kk, Gc,
                                                         (float*)Afp[i + 1], degp, ldM, ldn,
                                                         kchunk);
        }
        // ---- GCN on level i+1 ----
        float* outx = (i < 3) ? xsb[i + 1] : xtB;
        const float* pnext = (i < 3) ? (Pf + (i + 1) * H) : nullptr;
        int npown = (i < 3) ? npw[i + 1] : 0;
        int hascs = (i <= 1) ? 1 : 0;             // levels 3/4 get deg from gemm64_atomic
        int nparts = (i <= 1) ? (ldn >> 6) : 1;
        run_dense(stream, Afp[i + 1], abfL[i + 1], kk, ldn, xcur, perm[i], vals[i], nullptr,
                  nullptr, Wdf + i * (H * H), bdf + i * H, outx, degp, nparts, hascs,
                  disL + i * N0, (i < 3) ? 1 : 0, aggp, msgb, pnext, npown, keys);
        xcur = outx;
    }

    // ---- up path (dis cached in disL; unpool fused into rawmsg via invperm) ----
    for (int i = 0; i < 4; ++i) {
        int j = 3 - i;
        int nj = nlvl[j];
        if (i < 3) {
            int ldn = ldl[j];
            float* outx = (xcur == xtB) ? xtC : xtB;
            run_dense(stream, Afp[j], abfL[j], nj, ldn, xsb[j], nullptr, nullptr, xcur,
                      invpermL + j * N0, Wuf + i * (H * H), buf2 + i * H, outx, nullptr, 0, 0,
                      disL + (j - 1) * N0, 0, aggp, msgb, nullptr, 0, nullptr);
            xcur = outx;
        } else {
            msg3up_kernel<<<(N0 * 3 + 255) / 256, 256, 0, stream>>>(xs0, xcur, invpermL, Wlf, dis0,
                                                                    msgb, N0);
            cscagg_lsm_kernel<<<(N0 + 255) / 256, 256, 0, stream>>>(rowpD, srcs, msgb, dis0, fixb0,
                                                                    blf, (float*)d_out, N0);
        }
    }
}

// Round 8
// 425.391 us; speedup vs baseline: 1.0168x; 1.0168x over previous
//
#include <hip/hip_runtime.h>
#include <math.h>

#define H 32
#define N0 4096
#define EMAX 131072
#define APSTR (4096 * 32)

typedef __attribute__((ext_vector_type(4))) float floatx4;
typedef __attribute__((ext_vector_type(8))) short short8;

__device__ __forceinline__ unsigned short f2bf_bits(float v) {
    union { float f; unsigned u; } c;
    c.f = v;
    unsigned lsb = (c.u >> 16) & 1u;
    c.u += 0x7fffu + lsb;   // RNE; inputs here are small exact integers
    return (unsigned short)(c.u >> 16);
}

__device__ __forceinline__ float bf2f(unsigned short u) {
    union { unsigned x; float f; } c;
    c.x = (unsigned)u << 16;
    return c.f;
}

__device__ __forceinline__ float cvtA(float f) { return f; }
__device__ __forceinline__ float cvtA(unsigned short u) { return bf2f(u); }

// ---------------- sentinel ----------------
__global__ void fill_sentinel_kernel(float* out, int n) {
    int t = blockIdx.x * 256 + threadIdx.x;
    if (t < n) out[t] = 9.0f;
}

// ---------------- CSR build ----------------
__global__ void build_stats_kernel(const int* __restrict__ ei, int E, int* __restrict__ rowcnt,
                                   int* __restrict__ rowcntD, int* __restrict__ diagcnt) {
    int t = blockIdx.x * 256 + threadIdx.x;
    if (t >= E) return;
    int s = ei[t], d = ei[E + t];
    if ((unsigned)s >= N0 || (unsigned)d >= N0) return;
    atomicAdd(&rowcnt[s], 1);
    atomicAdd(&rowcntD[d], 1);
    if (s == d) atomicAdd(&diagcnt[s], 1);
}

// both scans in one pass: wave-level shfl scans (2 barriers total, integer-exact)
__global__ __launch_bounds__(1024) void scan2_kernel(const int* __restrict__ cntA, int* __restrict__ rowpA,
                                                     int* __restrict__ curA, const int* __restrict__ cntB,
                                                     int* __restrict__ rowpB, int* __restrict__ curB) {
    __shared__ int wsA[16], wsB[16], weA[16], weB[16];
    int tid = threadIdx.x;
    int lane = tid & 63, wid = tid >> 6;
    int base = tid * 4;
    int lA[4], lB[4];
    int sA = 0, sB = 0;
#pragma unroll
    for (int i = 0; i < 4; i++) { lA[i] = sA; sA += cntA[base + i]; }
#pragma unroll
    for (int i = 0; i < 4; i++) { lB[i] = sB; sB += cntB[base + i]; }
    int iA = sA, iB = sB;
#pragma unroll
    for (int off = 1; off < 64; off <<= 1) {
        int vA = __shfl_up(iA, off);
        int vB = __shfl_up(iB, off);
        if (lane >= off) { iA += vA; iB += vB; }
    }
    if (lane == 63) { wsA[wid] = iA; wsB[wid] = iB; }
    __syncthreads();
    if (tid < 16) {
        int a = wsA[tid], b = wsB[tid];
        int ia = a, ib = b;
#pragma unroll
        for (int off = 1; off < 16; off <<= 1) {
            int va = __shfl_up(ia, off);
            int vb = __shfl_up(ib, off);
            if (tid >= off) { ia += va; ib += vb; }
        }
        weA[tid] = ia - a;
        weB[tid] = ib - b;
    }
    __syncthreads();
    int preA = weA[wid] + iA - sA;
    int preB = weB[wid] + iB - sB;
#pragma unroll
    for (int i = 0; i < 4; i++) {
        int a = preA + lA[i], b = preB + lB[i];
        rowpA[base + i] = a; curA[base + i] = a;
        rowpB[base + i] = b; curB[base + i] = b;
    }
    if (tid == 1023) { rowpA[N0] = preA + sA; rowpB[N0] = preB + sB; }
}

// fused: CSR fill (blocks [0,nf)) + level-0 msg with inline degree finalize (rest)
__global__ void fillcsr_msg0_kernel(const int* __restrict__ ei, int E, int* __restrict__ cursor,
                                    int* __restrict__ cols, int* __restrict__ cursorD,
                                    int* __restrict__ srcs, const float* __restrict__ x,
                                    const float* __restrict__ Wb, const int* __restrict__ rcntD,
                                    const int* __restrict__ diagcnt, float* __restrict__ dis,
                                    float* __restrict__ fixb, float* __restrict__ msg, int n) {
    int nf = (E + 255) >> 8;
    int tid = threadIdx.x;
    if ((int)blockIdx.x < nf) {
        int t = blockIdx.x * 256 + tid;
        if (t >= E) return;
        int s = ei[t], d = ei[E + t];
        if ((unsigned)s >= N0 || (unsigned)d >= N0) return;
        int pos = atomicAdd(&cursor[s], 1);
        cols[pos] = d;
        int posD = atomicAdd(&cursorD[d], 1);
        srcs[posD] = s;
    } else {
        int idx = ((int)blockIdx.x - nf) * 256 + tid;
        if (idx >= n * 32) return;
        int i = idx >> 5, c = idx & 31;
        float fx = diagcnt[i] > 0 ? 0.f : 2.f;
        float dg = (float)rcntD[i] + fx;
        float di = dg > 0.f ? 1.f / sqrtf(dg) : 0.f;
        if (c == 0) { dis[i] = di; fixb[i] = fx; }
        float s = x[i * 3] * Wb[c] + x[i * 3 + 1] * Wb[32 + c] + x[i * 3 + 2] * Wb[64 + c];
        msg[idx] = s * di;
    }
}

// ---------------- level-0 fused augment+pool; A1 written as bf16 (exact small ints) ------
__global__ __launch_bounds__(256) void aug0_kernel(const int* __restrict__ rowp, const int* __restrict__ cols,
                                                   const int* __restrict__ perm, const int* __restrict__ invperm,
                                                   int kOut, int ldC, unsigned short* __restrict__ C) {
    __shared__ float row[2048];
    int a = blockIdx.x;
    int tid = threadIdx.x;
    for (int j = tid; j < ldC; j += 256) row[j] = 0.f;
    __syncthreads();
    if (a < kOut) {
        int pa = perm[a];
        int s0 = rowp[pa], s1 = rowp[pa + 1];
        int sub = tid & 7, grp = tid >> 3;   // 32 edge-lanes x 8 inner-lanes
        for (int e = s0 + grp; e < s1; e += 32) {
            int k = cols[e];
            if (sub == 0) {
                int ip = invperm[k];
                if (ip >= 0) atomicAdd(&row[ip], 2.0f);
            }
            int t1 = rowp[k + 1];
            for (int e2 = rowp[k] + sub; e2 < t1; e2 += 8) {
                int ip2 = invperm[cols[e2]];
                if (ip2 >= 0) atomicAdd(&row[ip2], 1.0f);
            }
        }
    }
    __syncthreads();
    for (int j = tid; j < ldC; j += 256)
        C[(long)a * ldC + j] = (j == a) ? 0 : f2bf_bits(row[j]);
}

// ---------------- deeper levels ----------------
// level 1->2: transpose-only gather (bf16) + zero GcT rows [kOut, ldn) + zero C accumulator.
// (row-gather of the A-operand is fused into mfma_aug's global loads)
__global__ void gatherABt_bf16_kernel(const unsigned short* __restrict__ M, int ldM,
                                      const int* __restrict__ invp, int kOut,
                                      unsigned short* __restrict__ GcT, int ldn,
                                      float* __restrict__ Cz) {
    __shared__ float t[32][33];
    __shared__ int rj[32];
    int tseg = (ldM >> 5) * (ldM >> 5);
    int zrow = (((ldn - kOut) * ldM) + 255) >> 8;
    int u = blockIdx.x;
    int tid = threadIdx.x;
    if (u < tseg) {
        int ntx = ldM >> 5;
        int bx = u % ntx, by = u / ntx;
        int j0 = bx * 32, k0 = by * 32;
        int tx = tid & 31, ty = tid >> 5;
        if (ty == 0) rj[tx] = invp[j0 + tx];
        __syncthreads();
        for (int y = ty; y < 32; y += 8)
            t[y][tx] = bf2f(M[(long)(k0 + y) * ldM + j0 + tx]);   // coalesced read
        __syncthreads();
        for (int y = ty; y < 32; y += 8) {
            int r = rj[y];
            if (r >= 0)
                GcT[(long)r * ldM + k0 + tx] =
                    f2bf_bits(t[tx][y] + ((k0 + tx) == (j0 + y) ? 1.f : 0.f));
        }
    } else if (u < tseg + zrow) {
        int e = (u - tseg) * 256 + tid;
        if (e < (ldn - kOut) * ldM) GcT[(long)kOut * ldM + e] = 0;
    } else {
        int t4 = (u - tseg - zrow) * 256 + tid;
        if (t4 < (ldn * ldn) >> 2) {
            floatx4 z = {0.f, 0.f, 0.f, 0.f};
            ((floatx4*)Cz)[t4] = z;
        }
    }
}

// fp32 levels: transpose-only gather -> GcT[b][k] + zero-rows + zero deg
__global__ void gatherT_kernel(const float* __restrict__ M, int ldM,
                               const int* __restrict__ invp, int kOut,
                               float* __restrict__ GcT, int ldn, float* __restrict__ deg) {
    __shared__ float t[32][33];
    __shared__ int rj[32];
    int tseg = (ldM >> 5) * (ldM >> 5);
    int zrow = (((ldn - kOut) * ldM) + 255) >> 8;
    int u = blockIdx.x;
    int tid = threadIdx.x;
    if (u < tseg) {
        int ntx = ldM >> 5;
        int bx = u % ntx, by = u / ntx;
        int j0 = bx * 32, k0 = by * 32;
        int tx = tid & 31, ty = tid >> 5;
        if (ty == 0) rj[tx] = invp[j0 + tx];
        __syncthreads();
        for (int y = ty; y < 32; y += 8)
            t[y][tx] = M[(long)(k0 + y) * ldM + j0 + tx];   // coalesced read
        __syncthreads();
        for (int y = ty; y < 32; y += 8) {
            int r = rj[y];
            if (r >= 0)
                GcT[(long)r * ldM + k0 + tx] = t[tx][y] + ((k0 + tx) == (j0 + y) ? 1.f : 0.f);
        }
    } else if (u < tseg + zrow) {
        int e = (u - tseg) * 256 + tid;
        if (e < (ldn - kOut) * ldM) GcT[(long)kOut * ldM + e] = 0.f;
    } else {
        int tt = (u - tseg - zrow) * 256 + tid;
        if (tt < ldn) deg[tt] = 0.f;
    }
}

// MFMA augment GEMM; A-operand row-gathered inline from bf16 A1 (perm + diag-add, zero rows >= kOut)
__global__ __launch_bounds__(256) void mfma_aug_kernel(const unsigned short* __restrict__ A1,
                                                       const int* __restrict__ perm, int kOut,
                                                       const unsigned short* __restrict__ Bop,
                                                       float* __restrict__ C, int K, int ldC, int kchunk) {
    __shared__ __align__(16) unsigned short lA[64 * 32];
    __shared__ __align__(16) unsigned short lB[64 * 32];
    const int tid = threadIdx.x;
    const int lane = tid & 63;
    const int w = tid >> 6;
    const int a0 = blockIdx.y * 64, b0 = blockIdx.x * 64;
    const int kbase = blockIdx.z * kchunk;
    const int r0 = tid >> 2;
    const int c8 = (tid & 3) * 8;
    const int arow = a0 + r0;
    const int pa = (arow < kOut) ? perm[arow] : -1;
    const unsigned short* gA = A1 + (pa >= 0 ? (long)pa * K : 0) + kbase + c8;
    const unsigned short* gB = Bop + (long)(b0 + r0) * K + kbase + c8;
    const int wm = (w & 1) * 32;
    const int wn = (w >> 1) * 32;
    const int lm = lane & 15;
    const int quad = lane >> 4;
    floatx4 acc[2][2];
#pragma unroll
    for (int i = 0; i < 2; i++)
#pragma unroll
        for (int j = 0; j < 2; j++) {
            floatx4 z = {0.f, 0.f, 0.f, 0.f};
            acc[i][j] = z;
        }
    for (int k0 = 0; k0 < kchunk; k0 += 32) {
        short8 va;
        if (pa >= 0) {
            va = *(const short8*)(gA + k0);
            int cb = kbase + c8 + k0;
            if (pa >= cb && pa < cb + 8) {
                int e = pa - cb;
                va[e] = (short)f2bf_bits(bf2f((unsigned short)va[e]) + 1.0f);
            }
        } else {
            short8 z = {0, 0, 0, 0, 0, 0, 0, 0};
            va = z;
        }
        short8 vb = *(const short8*)(gB + k0);
        __syncthreads();
        *(short8*)&lA[r0 * 32 + c8] = va;
        *(short8*)&lB[r0 * 32 + c8] = vb;
        __syncthreads();
        short8 af[2], bf[2];
#pragma unroll
        for (int mi = 0; mi < 2; mi++) af[mi] = *(const short8*)&lA[(wm + mi * 16 + lm) * 32 + quad * 8];
#pragma unroll
        for (int ni = 0; ni < 2; ni++) bf[ni] = *(const short8*)&lB[(wn + ni * 16 + lm) * 32 + quad * 8];
#pragma unroll
        for (int mi = 0; mi < 2; mi++)
#pragma unroll
            for (int ni = 0; ni < 2; ni++)
                acc[mi][ni] = __builtin_amdgcn_mfma_f32_16x16x32_bf16(af[mi], bf[ni], acc[mi][ni], 0, 0, 0);
    }
#pragma unroll
    for (int mi = 0; mi < 2; mi++)
#pragma unroll
        for (int ni = 0; ni < 2; ni++) {
            int col = b0 + wn + ni * 16 + lm;
#pragma unroll
            for (int r = 0; r < 4; r++) {
                int row = a0 + wm + mi * 16 + quad * 4 + r;
                if (row != col) atomicAdd(&C[(long)row * ldC + col], acc[mi][ni][r]);
            }
        }
}

// fp32 GEMM: A-operand row-gathered inline (perm + diag), B from GcT[b][K];
// streamed stores into Cpart k-slices (no atomics).
__global__ __launch_bounds__(256) void gemm64_kernel(const float* __restrict__ A,
                                                     const int* __restrict__ perm, int kOut,
                                                     const float* __restrict__ GcT,
                                                     float* __restrict__ Cpart, int K, int ldC, int kchunk) {
    __shared__ float As[32][68];
    __shared__ float Bs[32][68];
    const int tid = threadIdx.x;
    const int a0 = blockIdx.y * 64, b0 = blockIdx.x * 64;
    const int kbase = blockIdx.z * kchunk;
    float* Cz = Cpart + (long)blockIdx.z * ldC * ldC;
    const int tx = tid & 15, ty = tid >> 4;
    const int lr = tid >> 2;
    const int lk = (tid & 3) * 8;
    const int arow = a0 + lr;
    const int pa = (arow < kOut) ? perm[arow] : -1;
    const float* gA = A + (pa >= 0 ? (long)pa * K : 0) + lk + kbase;
    const float* gB = GcT + (long)(b0 + lr) * K + lk + kbase;
    float acc[4][4];
#pragma unroll
    for (int i = 0; i < 4; i++)
#pragma unroll
        for (int j = 0; j < 4; j++) acc[i][j] = 0.f;
    for (int k0 = 0; k0 < kchunk; k0 += 32) {
        float a8[8], b8[8];
        if (pa >= 0) {
#pragma unroll
            for (int i = 0; i < 8; i++) a8[i] = gA[k0 + i];
            int cb = kbase + lk + k0;
            if (pa >= cb && pa < cb + 8) a8[pa - cb] += 1.f;
        } else {
#pragma unroll
            for (int i = 0; i < 8; i++) a8[i] = 0.f;
        }
#pragma unroll
        for (int i = 0; i < 8; i++) b8[i] = gB[k0 + i];
        __syncthreads();
#pragma unroll
        for (int i = 0; i < 8; i++) As[lk + i][lr] = a8[i];
#pragma unroll
        for (int i = 0; i < 8; i++) Bs[lk + i][lr] = b8[i];
        __syncthreads();
#pragma unroll
        for (int k = 0; k < 32; k++) {
            floatx4 av = *(const floatx4*)&As[k][ty * 4];
            floatx4 bv = *(const floatx4*)&Bs[k][tx * 4];
#pragma unroll
            for (int i = 0; i < 4; i++)
#pragma unroll
                for (int j = 0; j < 4; j++) acc[i][j] += av[i] * bv[j];
        }
    }
#pragma unroll
    for (int i = 0; i < 4; i++)
#pragma unroll
        for (int j = 0; j < 4; j++) {
            int a = a0 + ty * 4 + i, b = b0 + tx * 4 + j;
            Cz[(long)a * ldC + b] = acc[i][j];
        }
}

// reduce k-split partials -> C, zero diag, accumulate column sums (deg) via atomics (exact ints)
__global__ void reduce_part_deg_kernel(const float* __restrict__ Cpart, float* __restrict__ C,
                                       int ldC, int ksplit, float* __restrict__ deg) {
    int t = blockIdx.x * 256 + threadIdx.x;
    long tot = (long)ldC * ldC;
    if (t >= tot) return;
    float s = 0.f;
    for (int z = 0; z < ksplit; z++) s += Cpart[(long)z * tot + t];
    int a = t / ldC, b = t % ldC;
    if (a == b) s = 0.f;
    C[t] = s;
    if (s != 0.f) atomicAdd(&deg[b], s);
}

// ---------------- K1: colsum partials (optional) || raw msg (no dis scaling) ----------------
template <typename AT>
__global__ void colsum_rawmsg_kernel(const AT* __restrict__ A, int ld, int hascs,
                                     const float* __restrict__ x, const int* __restrict__ perm,
                                     const float* __restrict__ vals, const float* __restrict__ xup,
                                     const int* __restrict__ invp, const float* __restrict__ Wb,
                                     float* __restrict__ degp, float* __restrict__ rm, int n) {
    int nc = hascs ? (ld >> 8) * (ld >> 6) : 0;
    int tid = threadIdx.x;
    if ((int)blockIdx.x < nc) {
        int gx = ld >> 8;
        int bi = blockIdx.x % gx, jb = blockIdx.x / gx;
        int i = bi * 256 + tid;
        int j0 = jb * 64;
        const AT* p = A + (long)j0 * ld + i;
        float s0 = 0.f, s1 = 0.f, s2 = 0.f, s3 = 0.f, s4 = 0.f, s5 = 0.f, s6 = 0.f, s7 = 0.f;
#pragma unroll
        for (int jq = 0; jq < 64; jq += 8) {
            float v[8];
#pragma unroll
            for (int q = 0; q < 8; q++) v[q] = cvtA(p[(long)(jq + q) * ld]);
            s0 += v[0]; s1 += v[1]; s2 += v[2]; s3 += v[3];
            s4 += v[4]; s5 += v[5]; s6 += v[6]; s7 += v[7];
        }
        float s = ((s0 + s1) + (s2 + s3)) + ((s4 + s5) + (s6 + s7));
        degp[(long)jb * ld + i] = s;
    } else {
        int idx = ((int)blockIdx.x - nc) * 256 + tid;
        if (idx >= ld * 32) return;
        int i = idx >> 5, c = idx & 31;
        float v = 0.f;
        if (i < n) {
            int src = perm ? perm[i] : i;
            float vs = vals ? vals[i] : 1.f;
            int ip = invp ? invp[i] : -1;
            float s = 0.f;
#pragma unroll
            for (int q = 0; q < 32; q++) {
                float xv = x[(long)src * 32 + q];
                if (ip >= 0) xv += xup[(long)ip * 32 + q];
                s += xv * Wb[q * 32 + c];
            }
            v = s * vs;
        }
        rm[idx] = v;
    }
}

// ---------------- aggT with inline dis_j scaling ----------------
template <typename AT>
__global__ __launch_bounds__(256) void aggTs_kernel(const AT* __restrict__ A,
                                                    const float* __restrict__ rm,
                                                    const float* __restrict__ degp, int nparts,
                                                    const float* __restrict__ disC,
                                                    float* __restrict__ aggp, int n, int ld, int jchunk) {
    __shared__ float As[64][64];
    __shared__ float Ms[64][32];
    __shared__ float sdisJ[256];
    const int tid = threadIdx.x;
    const int i0 = blockIdx.x * 64;
    const int j0 = blockIdx.y * jchunk;
    for (int j = tid; j < jchunk; j += 256) {
        int jj = j0 + j;
        float d;
        if (nparts) {
            float s = 0.f;
            for (int z = 0; z < nparts; z++) s += degp[(long)z * ld + jj];
            d = 1.f / sqrtf(s + 2.f);
        } else {
            d = disC[jj];
        }
        sdisJ[j] = d;
    }
    __syncthreads();
    const int il = tid & 63;
    const int cg = tid >> 6;
    const int i = i0 + il;
    const int mrow = tid >> 2;
    const int mc = (tid & 3) * 8;
    float acc[8];
#pragma unroll
    for (int q = 0; q < 8; q++) acc[q] = 0.f;
    for (int jb = j0; jb < j0 + jchunk; jb += 64) {
        AT a16[16];
        float m8[8];
#pragma unroll
        for (int q = 0; q < 16; q++) a16[q] = A[(long)(jb + cg + 4 * q) * ld + i0 + il];
#pragma unroll
        for (int q = 0; q < 8; q++) m8[q] = rm[(long)(jb + mrow) * 32 + mc + q];
        __syncthreads();
#pragma unroll
        for (int q = 0; q < 16; q++) As[cg + 4 * q][il] = cvtA(a16[q]);
        float ds = sdisJ[jb - j0 + mrow];
#pragma unroll
        for (int q = 0; q < 8; q++) Ms[mrow][mc + q] = m8[q] * ds;
        __syncthreads();
#pragma unroll
        for (int jl = 0; jl < 64; jl++) {
            float a = As[jl][il];
#pragma unroll
            for (int q = 0; q < 8; q++) acc[q] += a * Ms[jl][cg * 8 + q];
        }
        __syncthreads();
    }
    if (i < n) {
#pragma unroll
        for (int q = 0; q < 8; q++) aggp[(long)blockIdx.y * APSTR + (long)i * 32 + cg * 8 + q] = acc[q];
    }
}

// ---------------- epilogue: partial sum + dis finalize + self term + keys ----------------
__global__ void epi2_kernel(const float* __restrict__ aggp, int jsplit, const float* __restrict__ rm,
                            const float* __restrict__ degp, int nparts, float* __restrict__ disC,
                            int writeDis, int ld, const float* __restrict__ bb,
                            float* __restrict__ out, int n, const float* __restrict__ p, int npow,
                            unsigned long long* __restrict__ keys) {
    __shared__ float psh[32];
    if (p) {
        if (threadIdx.x < 32) psh[threadIdx.x] = p[threadIdx.x];
        __syncthreads();
    }
    int idx = blockIdx.x * 256 + threadIdx.x;
    int tot = (p ? npow : n) * 32;
    if (idx >= tot) return;
    int i = idx >> 5, c = idx & 31;
    float di;
    if (nparts) {
        float s = 0.f;
        for (int z = 0; z < nparts; z++) s += degp[(long)z * ld + i];
        di = 1.f / sqrtf(s + 2.f);
    } else {
        di = disC[i];
    }
    float v = 0.f;
    if (i < n) {
        float s = 0.f;
        for (int z = 0; z < jsplit; z++) s += aggp[(long)z * APSTR + idx];
        v = (s + 2.f * di * rm[idx]) * di + bb[c];
        v = fmaxf(v, 0.f);
        out[idx] = v;
    }
    if (writeDis && c == 0) disC[i] = di;
    if (p) {
        float pc = psh[c];
        float d = v * pc;
        float nq = pc * pc;
#pragma unroll
        for (int st = 16; st >= 1; st >>= 1) {
            d += __shfl_xor(d, st);
            nq += __shfl_xor(nq, st);
        }
        if (c == 0) {
            unsigned long long kk = 0ULL;
            if (i < n) {
                float sc = tanhf(d / sqrtf(nq));
                unsigned u = __float_as_uint(sc);
                u = (u & 0x80000000u) ? ~u : (u | 0x80000000u);
                kk = ((unsigned long long)u << 32) | (unsigned)(~i);
            }
            keys[i] = kk;
        }
    }
}

// level-0 sparse agg + epilogue + level-0 pooling keys (wave-reduced)
__global__ void cscagg_epi_keys_kernel(const int* __restrict__ rowpD, const int* __restrict__ srcs,
                                       const float* __restrict__ msg, const float* __restrict__ dis,
                                       const float* __restrict__ fixb, const float* __restrict__ bb,
                                       float* __restrict__ out, int n, const float* __restrict__ p,
                                       unsigned long long* __restrict__ keys) {
    __shared__ float psh[32];
    if (threadIdx.x < 32) psh[threadIdx.x] = p[threadIdx.x];
    __syncthreads();
    int idx = blockIdx.x * 256 + threadIdx.x;
    if (idx >= n * 32) return;
    int i = idx >> 5, c = idx & 31;
    float acc = 0.f;
    int e0 = rowpD[i], e1 = rowpD[i + 1];
    for (int e = e0; e < e1; e++) acc += msg[(long)srcs[e] * 32 + c];
    float v = (acc + fixb[i] * msg[idx]) * dis[i] + bb[c];
    v = fmaxf(v, 0.f);
    out[idx] = v;
    float pc = psh[c];
    float d = v * pc;
    float nq = pc * pc;
#pragma unroll
    for (int st = 16; st >= 1; st >>= 1) {
        d += __shfl_xor(d, st);
        nq += __shfl_xor(nq, st);
    }
    if (c == 0) {
        float sc = tanhf(d / sqrtf(nq));
        unsigned u = __float_as_uint(sc);
        u = (u & 0x80000000u) ? ~u : (u | 0x80000000u);
        keys[i] = ((unsigned long long)u << 32) | (unsigned)(~i);
    }
}

// final up-level msg (32->3) with fused unpool
__global__ void msg3up_kernel(const float* __restrict__ res, const float* __restrict__ xup,
                              const int* __restrict__ invp, const float* __restrict__ Wb,
                              const float* __restrict__ dis, float* __restrict__ msg, int n) {
    int idx = blockIdx.x * 256 + threadIdx.x;
    if (idx >= n * 3) return;
    int i = idx / 3, c = idx % 3;
    int ip = invp[i];
    float s = 0.f;
#pragma unroll
    for (int q = 0; q < 32; q++) {
        float xv = res[(long)i * 32 + q];
        if (ip >= 0) xv += xup[(long)ip * 32 + q];
        s += xv * Wb[q * 3 + c];
    }
    msg[idx] = s * dis[i];
}

// final sparse GCN epilogue + log_softmax fused, writes d_out directly
__global__ void cscagg_lsm_kernel(const int* __restrict__ rowpD, const int* __restrict__ srcs,
                                  const float* __restrict__ msg, const float* __restrict__ dis,
                                  const float* __restrict__ fixb, const float* __restrict__ bb,
                                  float* __restrict__ out, int n) {
    int i = blockIdx.x * 256 + threadIdx.x;
    if (i >= n) return;
    float a0 = 0.f, a1 = 0.f, a2 = 0.f;
    int e0 = rowpD[i], e1 = rowpD[i + 1];
    for (int e = e0; e < e1; e++) {
        const float* m = &msg[(long)srcs[e] * 3];
        a0 += m[0]; a1 += m[1]; a2 += m[2];
    }
    float di = dis[i], fx = fixb[i];
    float v0 = (a0 + fx * msg[i * 3]) * di + bb[0];
    float v1 = (a1 + fx * msg[i * 3 + 1]) * di + bb[1];
    float v2 = (a2 + fx * msg[i * 3 + 2]) * di + bb[2];
    float m = fmaxf(v0, fmaxf(v1, v2));
    float s = expf(v0 - m) + expf(v1 - m) + expf(v2 - m);
    float l = m + logf(s);
    out[i * 3] = v0 - l;
    out[i * 3 + 1] = v1 - l;
    out[i * 3 + 2] = v2 - l;
}

// standalone top-k rank
__global__ __launch_bounds__(256) void topk_rank_kernel(const unsigned long long* __restrict__ keys,
                                                        int npow, int k, int* __restrict__ perm,
                                                        float* __restrict__ vals,
                                                        int* __restrict__ invperm) {
    __shared__ unsigned long long ks[4096];
    __shared__ int psum[256];
    const int tid = threadIdx.x;
    for (int t = tid; t < npow; t += 256) ks[t] = keys[t];
    __syncthreads();
    const int m = tid & 15;
    const int chunk = tid >> 4;
    const int myi = blockIdx.x * 16 + m;
    unsigned long long my = ks[myi];
    const int cl = npow >> 4;
    const unsigned long long* base = &ks[chunk * cl];
    int r = 0;
#pragma unroll 4
    for (int j = 0; j < cl; j++) r += (base[j] > my) ? 1 : 0;
    psum[chunk * 16 + m] = r;
    __syncthreads();
    if (tid < 16) {
        int mk_i = blockIdx.x * 16 + tid;
        unsigned long long mk = ks[mk_i];
        int rank = 0;
#pragma unroll
        for (int c = 0; c < 16; c++) rank += psum[c * 16 + tid];
        invperm[mk_i] = (rank < k) ? rank : -1;
        if (rank < k) {
            perm[rank] = (int)(~(unsigned)mk);
            unsigned u = (unsigned)(mk >> 32);
            u = (u & 0x80000000u) ? (u ^ 0x80000000u) : ~u;
            vals[rank] = __uint_as_float(u);
        }
    }
}

// ---------------- host ----------------
static void run_dense(hipStream_t st, const void* A, int abf, int n, int ld, const float* x,
                      const int* perm, const float* vals, const float* xup, const int* invp,
                      const float* Wt, const float* bt, float* out,
                      float* degp, int nparts, int hascs, float* disC, int writeDis,
                      float* aggp, float* rm,
                      const float* pnext, int npow, unsigned long long* keys) {
    {
        int nc = hascs ? (ld >> 8) * (ld >> 6) : 0;
        int g = nc + (ld * 32 + 255) / 256;
        if (abf)
            colsum_rawmsg_kernel<unsigned short><<<g, 256, 0, st>>>(
                (const unsigned short*)A, ld, hascs, x, perm, vals, xup, invp, Wt, degp, rm, n);
        else
            colsum_rawmsg_kernel<float><<<g, 256, 0, st>>>(
                (const float*)A, ld, hascs, x, perm, vals, xup, invp, Wt, degp, rm, n);
    }
    int jsplit = (ld >= 256) ? (ld >> 8) : 1;
    if (jsplit < 1) jsplit = 1;
    int jchunk = ld / jsplit;
    dim3 ga(ld / 64, jsplit);
    if (abf)
        aggTs_kernel<unsigned short><<<ga, 256, 0, st>>>((const unsigned short*)A, rm,
                                                         nparts ? degp : nullptr, nparts, disC,
                                                         aggp, n, ld, jchunk);
    else
        aggTs_kernel<float><<<ga, 256, 0, st>>>((const float*)A, rm, nparts ? degp : nullptr,
                                                nparts, disC, aggp, n, ld, jchunk);
    int gme = ((pnext ? npow : n) * 32 + 255) / 256;
    epi2_kernel<<<gme, 256, 0, st>>>(aggp, jsplit, rm, nparts ? degp : nullptr, nparts, disC,
                                     writeDis, ld, bt, out, n, pnext, npow, keys);
}

extern "C" void kernel_launch(void* const* d_in, const int* in_sizes, int n_in,
                              void* d_out, int out_size, void* d_ws, size_t ws_size,
                              hipStream_t stream) {
    const float* x0f = (const float*)d_in[0];
    const int* eidx = (const int*)d_in[1];
    const float* W0f = (const float*)d_in[2];
    const float* b0f = (const float*)d_in[3];
    const float* Wdf = (const float*)d_in[4];
    const float* bdf = (const float*)d_in[5];
    const float* Pf = (const float*)d_in[6];
    const float* Wuf = (const float*)d_in[7];
    const float* buf2 = (const float*)d_in[8];
    const float* Wlf = (const float*)d_in[9];
    const float* blf = (const float*)d_in[10];
    const int E = in_sizes[1] / 2;

    unsigned char* w = (unsigned char*)d_ws;
    size_t off = 0;
    auto alloc = [&](size_t bytes) -> void* {
        void* p = w + off;
        off += (bytes + 255) & ~(size_t)255;
        return p;
    };
    int* rowcnt = (int*)alloc(N0 * 4);
    int* rowcntD = (int*)alloc(N0 * 4);
    int* diagcnt = (int*)alloc(N0 * 4);
    int* rowp = (int*)alloc((N0 + 1) * 4);
    int* rowpD = (int*)alloc((N0 + 1) * 4);
    int* cursor = (int*)alloc(N0 * 4);
    int* cursorD = (int*)alloc(N0 * 4);
    int* cols = (int*)alloc((size_t)EMAX * 4);
    int* srcs = (int*)alloc((size_t)EMAX * 4);
    float* dis0 = (float*)alloc(N0 * 4);
    float* fixb0 = (float*)alloc(N0 * 4);
    unsigned long long* keys = (unsigned long long*)alloc((size_t)N0 * 8);
    unsigned short* A1 = (unsigned short*)alloc((size_t)2048 * 2048 * 2);   // bf16 exact ints
    float* A2 = (float*)alloc((size_t)1024 * 1024 * 4);
    float* A3 = (float*)alloc((size_t)512 * 512 * 4);
    float* A4 = (float*)alloc((size_t)256 * 256 * 4);
    float* Gc = (float*)alloc((size_t)2048 * 1024 * 4);
    unsigned short* GcTb = (unsigned short*)alloc((size_t)1024 * 2048 * 2);
    float* Cpart = (float*)alloc((size_t)8 * 512 * 512 * 4);
    float* degp = (float*)alloc((size_t)32 * 2048 * 4);
    float* aggp = (float*)alloc((size_t)8 * APSTR * 4);
    float* xs0 = (float*)alloc((size_t)N0 * H * 4);
    float* xs1 = (float*)alloc((size_t)2000 * H * 4);
    float* xs2 = (float*)alloc((size_t)1000 * H * 4);
    float* xs3 = (float*)alloc((size_t)500 * H * 4);
    float* xtB = (float*)alloc((size_t)N0 * H * 4);
    float* xtC = (float*)alloc((size_t)N0 * H * 4);
    float* msgb = (float*)alloc((size_t)N0 * H * 4);
    float* disL = (float*)alloc((size_t)4 * N0 * 4);
    int* invpermL = (int*)alloc((size_t)4 * N0 * 4);
    const int ksz[4] = {2000, 1000, 500, 250};
    int* perm[4];
    float* vals[4];
    for (int i = 0; i < 4; i++) perm[i] = (int*)alloc((size_t)ksz[i] * 4);
    for (int i = 0; i < 4; i++) vals[i] = (float*)alloc((size_t)ksz[i] * 4);

    if (off > ws_size) {
        fill_sentinel_kernel<<<(out_size + 255) / 256, 256, 0, stream>>>((float*)d_out, out_size);
        return;
    }

    const int nlvl[5] = {N0, 2000, 1000, 500, 250};
    const int ldl[5] = {N0, 2048, 1024, 512, 256};
    const int npw[4] = {4096, 2048, 1024, 512};
    void* Afp[5] = {nullptr, A1, A2, A3, A4};
    const int abfL[5] = {0, 1, 0, 0, 0};
    float* xsb[4] = {xs0, xs1, xs2, xs3};

    // ---- CSR build + level-0 stats ----
    hipMemsetAsync(rowcnt, 0, (size_t)N0 * 3 * 4, stream);
    build_stats_kernel<<<(E + 255) / 256, 256, 0, stream>>>(eidx, E, rowcnt, rowcntD, diagcnt);
    scan2_kernel<<<1, 1024, 0, stream>>>(rowcnt, rowp, cursor, rowcntD, rowpD, cursorD);
    {
        int nf = (E + 255) / 256;
        int nm = (N0 * H + 255) / 256;
        fillcsr_msg0_kernel<<<nf + nm, 256, 0, stream>>>(eidx, E, cursor, cols, cursorD, srcs,
                                                         x0f, W0f, rowcntD, diagcnt, dis0, fixb0,
                                                         msgb, N0);
    }
    cscagg_epi_keys_kernel<<<(N0 * H + 255) / 256, 256, 0, stream>>>(rowpD, srcs, msgb, dis0, fixb0,
                                                                     b0f, xs0, N0, Pf, keys);
    float* xcur = xs0;

    // ---- down path ----
    for (int i = 0; i < 4; ++i) {
        int kk = ksz[i], ldn = ldl[i + 1];
        topk_rank_kernel<<<npw[i] / 16, 256, 0, stream>>>(keys, npw[i], kk, perm[i], vals[i],
                                                          invpermL + i * N0);
        // ---- build A_{i+1} ----
        if (i == 0) {
            aug0_kernel<<<ldn, 256, 0, stream>>>(rowp, cols, perm[0], invpermL, kk, ldn, A1);
        } else if (i == 1) {
            int ldM = ldl[i];
            int tseg = (ldM >> 5) * (ldM >> 5);
            int zrow = (((ldn - kk) * ldM) + 255) >> 8;
            int zseg = ((ldn * ldn) / 4 + 255) / 256;
            gatherABt_bf16_kernel<<<tseg + zrow + zseg, 256, 0, stream>>>(
                A1, ldM, invpermL + i * N0, kk, GcTb, ldn, A2);
            int ksplit = 2;
            int kchunk = ldM / ksplit;
            dim3 gg(ldn / 64, ldn / 64, ksplit);
            mfma_aug_kernel<<<gg, 256, 0, stream>>>(A1, perm[i], kk, GcTb, A2, ldM, ldn, kchunk);
        } else {
            int ldM = ldl[i];
            int tseg = (ldM >> 5) * (ldM >> 5);
            int zrow = (((ldn - kk) * ldM) + 255) >> 8;
            int dseg = (ldn + 255) / 256;
            gatherT_kernel<<<tseg + zrow + dseg, 256, 0, stream>>>(
                (const float*)Afp[i], ldM, invpermL + i * N0, kk, Gc, ldn, degp);
            int ksplit = 8;
            int kchunk = ldM / ksplit;
            dim3 gg(ldn / 64, ldn / 64, ksplit);
            gemm64_kernel<<<gg, 256, 0, stream>>>((const float*)Afp[i], perm[i], kk, Gc, Cpart,
                                                  ldM, ldn, kchunk);
            long tot = (long)ldn * ldn;
            reduce_part_deg_kernel<<<(tot + 255) / 256, 256, 0, stream>>>(Cpart, (float*)Afp[i + 1],
                                                                          ldn, ksplit, degp);
        }
        // ---- GCN on level i+1 ----
        float* outx = (i < 3) ? xsb[i + 1] : xtB;
        const float* pnext = (i < 3) ? (Pf + (i + 1) * H) : nullptr;
        int npown = (i < 3) ? npw[i + 1] : 0;
        int hascs = (i <= 1) ? 1 : 0;             // levels 3/4 get deg from reduce_part_deg
        int nparts = (i <= 1) ? (ldn >> 6) : 1;
        run_dense(stream, Afp[i + 1], abfL[i + 1], kk, ldn, xcur, perm[i], vals[i], nullptr,
                  nullptr, Wdf + i * (H * H), bdf + i * H, outx, degp, nparts, hascs,
                  disL + i * N0, (i < 3) ? 1 : 0, aggp, msgb, pnext, npown, keys);
        xcur = outx;
    }

    // ---- up path (dis cached in disL; unpool fused into rawmsg via invperm) ----
    for (int i = 0; i < 4; ++i) {
        int j = 3 - i;
        int nj = nlvl[j];
        if (i < 3) {
            int ldn = ldl[j];
            float* outx = (xcur == xtB) ? xtC : xtB;
            run_dense(stream, Afp[j], abfL[j], nj, ldn, xsb[j], nullptr, nullptr, xcur,
                      invpermL + j * N0, Wuf + i * (H * H), buf2 + i * H, outx, nullptr, 0, 0,
                      disL + (j - 1) * N0, 0, aggp, msgb, nullptr, 0, nullptr);
            xcur = outx;
        } else {
            msg3up_kernel<<<(N0 * 3 + 255) / 256, 256, 0, stream>>>(xs0, xcur, invpermL, Wlf, dis0,
                                                                    msgb, N0);
            cscagg_lsm_kernel<<<(N0 + 255) / 256, 256, 0, stream>>>(rowpD, srcs, msgb, dis0, fixb0,
                                                                    blf, (float*)d_out, N0);
        }
    }
}

// Round 9
// 420.006 us; speedup vs baseline: 1.0299x; 1.0128x over previous
//
#include <hip/hip_runtime.h>
#include <math.h>

#define H 32
#define N0 4096
#define EMAX 131072
#define APSTR (4096 * 32)

typedef __attribute__((ext_vector_type(4))) float floatx4;
typedef __attribute__((ext_vector_type(8))) short short8;

__device__ __forceinline__ unsigned short f2bf_bits(float v) {
    union { float f; unsigned u; } c;
    c.f = v;
    unsigned lsb = (c.u >> 16) & 1u;
    c.u += 0x7fffu + lsb;   // RNE; inputs here are small exact integers
    return (unsigned short)(c.u >> 16);
}

__device__ __forceinline__ float bf2f(unsigned short u) {
    union { unsigned x; float f; } c;
    c.x = (unsigned)u << 16;
    return c.f;
}

__device__ __forceinline__ float cvtA(float f) { return f; }
__device__ __forceinline__ float cvtA(unsigned short u) { return bf2f(u); }

// ---------------- sentinel ----------------
__global__ void fill_sentinel_kernel(float* out, int n) {
    int t = blockIdx.x * 256 + threadIdx.x;
    if (t < n) out[t] = 9.0f;
}

// ---------------- CSR build ----------------
__global__ void build_stats_kernel(const int* __restrict__ ei, int E, int* __restrict__ rowcnt,
                                   int* __restrict__ rowcntD, int* __restrict__ diagcnt) {
    int t = blockIdx.x * 256 + threadIdx.x;
    if (t >= E) return;
    int s = ei[t], d = ei[E + t];
    if ((unsigned)s >= N0 || (unsigned)d >= N0) return;
    atomicAdd(&rowcnt[s], 1);
    atomicAdd(&rowcntD[d], 1);
    if (s == d) atomicAdd(&diagcnt[s], 1);
}

// both scans in one pass: wave-level shfl scans (2 barriers total, integer-exact)
__global__ __launch_bounds__(1024) void scan2_kernel(const int* __restrict__ cntA, int* __restrict__ rowpA,
                                                     int* __restrict__ curA, const int* __restrict__ cntB,
                                                     int* __restrict__ rowpB, int* __restrict__ curB) {
    __shared__ int wsA[16], wsB[16], weA[16], weB[16];
    int tid = threadIdx.x;
    int lane = tid & 63, wid = tid >> 6;
    int base = tid * 4;
    int lA[4], lB[4];
    int sA = 0, sB = 0;
#pragma unroll
    for (int i = 0; i < 4; i++) { lA[i] = sA; sA += cntA[base + i]; }
#pragma unroll
    for (int i = 0; i < 4; i++) { lB[i] = sB; sB += cntB[base + i]; }
    int iA = sA, iB = sB;
#pragma unroll
    for (int off = 1; off < 64; off <<= 1) {
        int vA = __shfl_up(iA, off);
        int vB = __shfl_up(iB, off);
        if (lane >= off) { iA += vA; iB += vB; }
    }
    if (lane == 63) { wsA[wid] = iA; wsB[wid] = iB; }
    __syncthreads();
    if (tid < 16) {
        int a = wsA[tid], b = wsB[tid];
        int ia = a, ib = b;
#pragma unroll
        for (int off = 1; off < 16; off <<= 1) {
            int va = __shfl_up(ia, off);
            int vb = __shfl_up(ib, off);
            if (tid >= off) { ia += va; ib += vb; }
        }
        weA[tid] = ia - a;
        weB[tid] = ib - b;
    }
    __syncthreads();
    int preA = weA[wid] + iA - sA;
    int preB = weB[wid] + iB - sB;
#pragma unroll
    for (int i = 0; i < 4; i++) {
        int a = preA + lA[i], b = preB + lB[i];
        rowpA[base + i] = a; curA[base + i] = a;
        rowpB[base + i] = b; curB[base + i] = b;
    }
    if (tid == 1023) { rowpA[N0] = preA + sA; rowpB[N0] = preB + sB; }
}

// fused: CSR fill (blocks [0,nf)) + level-0 msg with inline degree finalize (rest)
__global__ void fillcsr_msg0_kernel(const int* __restrict__ ei, int E, int* __restrict__ cursor,
                                    int* __restrict__ cols, int* __restrict__ cursorD,
                                    int* __restrict__ srcs, const float* __restrict__ x,
                                    const float* __restrict__ Wb, const int* __restrict__ rcntD,
                                    const int* __restrict__ diagcnt, float* __restrict__ dis,
                                    float* __restrict__ fixb, float* __restrict__ msg, int n) {
    int nf = (E + 255) >> 8;
    int tid = threadIdx.x;
    if ((int)blockIdx.x < nf) {
        int t = blockIdx.x * 256 + tid;
        if (t >= E) return;
        int s = ei[t], d = ei[E + t];
        if ((unsigned)s >= N0 || (unsigned)d >= N0) return;
        int pos = atomicAdd(&cursor[s], 1);
        cols[pos] = d;
        int posD = atomicAdd(&cursorD[d], 1);
        srcs[posD] = s;
    } else {
        int idx = ((int)blockIdx.x - nf) * 256 + tid;
        if (idx >= n * 32) return;
        int i = idx >> 5, c = idx & 31;
        float fx = diagcnt[i] > 0 ? 0.f : 2.f;
        float dg = (float)rcntD[i] + fx;
        float di = dg > 0.f ? 1.f / sqrtf(dg) : 0.f;
        if (c == 0) { dis[i] = di; fixb[i] = fx; }
        float s = x[i * 3] * Wb[c] + x[i * 3 + 1] * Wb[32 + c] + x[i * 3 + 2] * Wb[64 + c];
        msg[idx] = s * di;
    }
}

// ---------------- level-0 fused augment+pool; A1 written as bf16 (exact small ints) ------
__global__ __launch_bounds__(256) void aug0_kernel(const int* __restrict__ rowp, const int* __restrict__ cols,
                                                   const int* __restrict__ perm, const int* __restrict__ invperm,
                                                   int kOut, int ldC, unsigned short* __restrict__ C) {
    __shared__ float row[2048];
    int a = blockIdx.x;
    int tid = threadIdx.x;
    for (int j = tid; j < ldC; j += 256) row[j] = 0.f;
    __syncthreads();
    if (a < kOut) {
        int pa = perm[a];
        int s0 = rowp[pa], s1 = rowp[pa + 1];
        int sub = tid & 7, grp = tid >> 3;   // 32 edge-lanes x 8 inner-lanes
        for (int e = s0 + grp; e < s1; e += 32) {
            int k = cols[e];
            if (sub == 0) {
                int ip = invperm[k];
                if (ip >= 0) atomicAdd(&row[ip], 2.0f);
            }
            int t1 = rowp[k + 1];
            for (int e2 = rowp[k] + sub; e2 < t1; e2 += 8) {
                int ip2 = invperm[cols[e2]];
                if (ip2 >= 0) atomicAdd(&row[ip2], 1.0f);
            }
        }
    }
    __syncthreads();
    for (int j = tid; j < ldC; j += 256)
        C[(long)a * ldC + j] = (j == a) ? 0 : f2bf_bits(row[j]);
}

// ---------------- deeper levels: fused pre-gathered operands + GEMM ----------------
// level 1->2: M is bf16 A1. (1) row-gather Gr, (2) coalesced invperm-keyed transpose -> GcT,
// (3) zero GcT rows [kOut, ldn), (4) zero C accumulator, (5) zero deg.
__global__ void gatherAB_bf16_kernel(const unsigned short* __restrict__ M, int ldM,
                                     const int* __restrict__ perm, const int* __restrict__ invp,
                                     int kOut, unsigned short* __restrict__ Gr,
                                     unsigned short* __restrict__ GcT, int ldn,
                                     float* __restrict__ Cz, float* __restrict__ deg) {
    __shared__ float t[32][33];
    __shared__ int rj[32];
    int half = (ldM >> 8) * ldn;
    int tseg = (ldM >> 5) * (ldM >> 5);
    int zrow = (((ldn - kOut) * ldM) + 255) >> 8;
    int zseg = ((ldn * ldn) / 4 + 255) / 256;
    int u = blockIdx.x;
    int tid = threadIdx.x;
    if (u < half) {
        int gx = ldM >> 8;
        int a = u / gx;
        int k = (u % gx) * 256 + tid;
        float v = 0.f;
        if (a < kOut) {
            int pa = perm[a];
            v = bf2f(M[(long)pa * ldM + k]) + (k == pa ? 1.f : 0.f);
        }
        Gr[(long)a * ldM + k] = f2bf_bits(v);
    } else if (u < half + tseg) {
        u -= half;
        int ntx = ldM >> 5;
        int bx = u % ntx, by = u / ntx;
        int j0 = bx * 32, k0 = by * 32;
        int tx = tid & 31, ty = tid >> 5;
        if (ty == 0) rj[tx] = invp[j0 + tx];
        __syncthreads();
        for (int y = ty; y < 32; y += 8)
            t[y][tx] = bf2f(M[(long)(k0 + y) * ldM + j0 + tx]);   // coalesced read
        __syncthreads();
        for (int y = ty; y < 32; y += 8) {
            int r = rj[y];
            if (r >= 0)
                GcT[(long)r * ldM + k0 + tx] =
                    f2bf_bits(t[tx][y] + ((k0 + tx) == (j0 + y) ? 1.f : 0.f));
        }
    } else if (u < half + tseg + zrow) {
        int e = (u - half - tseg) * 256 + tid;
        if (e < (ldn - kOut) * ldM) GcT[(long)kOut * ldM + e] = 0;
    } else if (u < half + tseg + zrow + zseg) {
        int t4 = (u - half - tseg - zrow) * 256 + tid;
        if (t4 < (ldn * ldn) >> 2) {
            floatx4 z = {0.f, 0.f, 0.f, 0.f};
            ((floatx4*)Cz)[t4] = z;
        }
    } else {
        int tt = (u - half - tseg - zrow - zseg) * 256 + tid;
        if (tt < ldn) deg[tt] = 0.f;
    }
}

// fp32 version: row-gather Gr + coalesced transpose -> GcT[b][k] (fp32) + zero-rows + deg zero
__global__ void gatherGT_kernel(const float* __restrict__ M, int ldM, const int* __restrict__ perm,
                                const int* __restrict__ invp, int kOut,
                                float* __restrict__ Gr, float* __restrict__ GcT, int ldn,
                                float* __restrict__ deg) {
    __shared__ float t[32][33];
    __shared__ int rj[32];
    int half = (ldM >> 8) * ldn;
    int tseg = (ldM >> 5) * (ldM >> 5);
    int zrow = (((ldn - kOut) * ldM) + 255) >> 8;
    int u = blockIdx.x;
    int tid = threadIdx.x;
    if (u < half) {
        int gx = ldM >> 8;
        int a = u / gx;
        int k = (u % gx) * 256 + tid;
        float v = 0.f;
        if (a < kOut) {
            int pa = perm[a];
            v = M[(long)pa * ldM + k] + (k == pa ? 1.f : 0.f);
        }
        Gr[(long)a * ldM + k] = v;
    } else if (u < half + tseg) {
        u -= half;
        int ntx = ldM >> 5;
        int bx = u % ntx, by = u / ntx;
        int j0 = bx * 32, k0 = by * 32;
        int tx = tid & 31, ty = tid >> 5;
        if (ty == 0) rj[tx] = invp[j0 + tx];
        __syncthreads();
        for (int y = ty; y < 32; y += 8)
            t[y][tx] = M[(long)(k0 + y) * ldM + j0 + tx];   // coalesced read
        __syncthreads();
        for (int y = ty; y < 32; y += 8) {
            int r = rj[y];
            if (r >= 0)
                GcT[(long)r * ldM + k0 + tx] = t[tx][y] + ((k0 + tx) == (j0 + y) ? 1.f : 0.f);
        }
    } else if (u < half + tseg + zrow) {
        int e = (u - half - tseg) * 256 + tid;
        if (e < (ldn - kOut) * ldM) GcT[(long)kOut * ldM + e] = 0.f;
    } else {
        int tt = (u - half - tseg - zrow) * 256 + tid;
        if (tt < ldn) deg[tt] = 0.f;
    }
}

// MFMA augment GEMM + fused column-sum (diag-excluded) -> deg atomics (exact ints, order-free)
__global__ __launch_bounds__(256) void mfma_aug_kernel(const unsigned short* __restrict__ Aop,
                                                       const unsigned short* __restrict__ Bop,
                                                       float* __restrict__ C, float* __restrict__ deg,
                                                       int K, int ldC, int kchunk) {
    __shared__ __align__(16) unsigned short lA[64 * 32];
    __shared__ __align__(16) unsigned short lB[64 * 32];
    const int tid = threadIdx.x;
    const int lane = tid & 63;
    const int w = tid >> 6;
    const int a0 = blockIdx.y * 64, b0 = blockIdx.x * 64;
    const int kbase = blockIdx.z * kchunk;
    const int r0 = tid >> 2;
    const int c8 = (tid & 3) * 8;
    const unsigned short* gA = Aop + (long)(a0 + r0) * K + kbase + c8;
    const unsigned short* gB = Bop + (long)(b0 + r0) * K + kbase + c8;
    const int wm = (w & 1) * 32;
    const int wn = (w >> 1) * 32;
    const int lm = lane & 15;
    const int quad = lane >> 4;
    floatx4 acc[2][2];
#pragma unroll
    for (int i = 0; i < 2; i++)
#pragma unroll
        for (int j = 0; j < 2; j++) {
            floatx4 z = {0.f, 0.f, 0.f, 0.f};
            acc[i][j] = z;
        }
    for (int k0 = 0; k0 < kchunk; k0 += 32) {
        short8 va = *(const short8*)(gA + k0);
        short8 vb = *(const short8*)(gB + k0);
        __syncthreads();
        *(short8*)&lA[r0 * 32 + c8] = va;
        *(short8*)&lB[r0 * 32 + c8] = vb;
        __syncthreads();
        short8 af[2], bf[2];
#pragma unroll
        for (int mi = 0; mi < 2; mi++) af[mi] = *(const short8*)&lA[(wm + mi * 16 + lm) * 32 + quad * 8];
#pragma unroll
        for (int ni = 0; ni < 2; ni++) bf[ni] = *(const short8*)&lB[(wn + ni * 16 + lm) * 32 + quad * 8];
#pragma unroll
        for (int mi = 0; mi < 2; mi++)
#pragma unroll
            for (int ni = 0; ni < 2; ni++)
                acc[mi][ni] = __builtin_amdgcn_mfma_f32_16x16x32_bf16(af[mi], bf[ni], acc[mi][ni], 0, 0, 0);
    }
#pragma unroll
    for (int mi = 0; mi < 2; mi++)
#pragma unroll
        for (int ni = 0; ni < 2; ni++) {
            int col = b0 + wn + ni * 16 + lm;
#pragma unroll
            for (int r = 0; r < 4; r++) {
                int row = a0 + wm + mi * 16 + quad * 4 + r;
                if (row != col) atomicAdd(&C[(long)row * ldC + col], acc[mi][ni][r]);
            }
        }
    // fused column-sum (diag excluded): 8 partials per column, LDS reduce, 64 atomics/block
    __syncthreads();
    float* colp = (float*)lA;                     // 64 cols x 8 partials (2 KB of the 4 KB lA)
    float p0 = 0.f, p1 = 0.f;
    int col0 = b0 + wn + lm;
    int col1 = b0 + wn + 16 + lm;
#pragma unroll
    for (int mi = 0; mi < 2; mi++)
#pragma unroll
        for (int r = 0; r < 4; r++) {
            int row = a0 + wm + mi * 16 + quad * 4 + r;
            p0 += (row != col0) ? acc[mi][0][r] : 0.f;
            p1 += (row != col1) ? acc[mi][1][r] : 0.f;
        }
    int pidx = quad + ((w & 1) << 2);
    colp[(wn + lm) * 8 + pidx] = p0;
    colp[(wn + 16 + lm) * 8 + pidx] = p1;
    __syncthreads();
    if (tid < 64) {
        float s = 0.f;
#pragma unroll
        for (int q = 0; q < 8; q++) s += colp[tid * 8 + q];
        if (s != 0.f) atomicAdd(&deg[b0 + tid], s);
    }
}

// B operand read row-major from GcT[b][K]
__global__ __launch_bounds__(256) void gemm64_kernel(const float* __restrict__ Gr,
                                                     const float* __restrict__ GcT,
                                                     float* __restrict__ Cpart, int K, int ldC, int kchunk) {
    __shared__ float As[32][68];
    __shared__ float Bs[32][68];
    const int tid = threadIdx.x;
    const int a0 = blockIdx.y * 64, b0 = blockIdx.x * 64;
    const int kbase = blockIdx.z * kchunk;
    float* Cz = Cpart + (long)blockIdx.z * ldC * ldC;
    const int tx = tid & 15, ty = tid >> 4;
    const int lr = tid >> 2;
    const int lk = (tid & 3) * 8;
    const float* gA = Gr + (long)(a0 + lr) * K + lk + kbase;
    const float* gB = GcT + (long)(b0 + lr) * K + lk + kbase;
    float acc[4][4];
#pragma unroll
    for (int i = 0; i < 4; i++)
#pragma unroll
        for (int j = 0; j < 4; j++) acc[i][j] = 0.f;
    for (int k0 = 0; k0 < kchunk; k0 += 32) {
        float a8[8], b8[8];
#pragma unroll
        for (int i = 0; i < 8; i++) a8[i] = gA[k0 + i];
#pragma unroll
        for (int i = 0; i < 8; i++) b8[i] = gB[k0 + i];
        __syncthreads();
#pragma unroll
        for (int i = 0; i < 8; i++) As[lk + i][lr] = a8[i];
#pragma unroll
        for (int i = 0; i < 8; i++) Bs[lk + i][lr] = b8[i];
        __syncthreads();
#pragma unroll
        for (int k = 0; k < 32; k++) {
            floatx4 av = *(const floatx4*)&As[k][ty * 4];
            floatx4 bv = *(const floatx4*)&Bs[k][tx * 4];
#pragma unroll
            for (int i = 0; i < 4; i++)
#pragma unroll
                for (int j = 0; j < 4; j++) acc[i][j] += av[i] * bv[j];
        }
    }
#pragma unroll
    for (int i = 0; i < 4; i++)
#pragma unroll
        for (int j = 0; j < 4; j++) {
            int a = a0 + ty * 4 + i, b = b0 + tx * 4 + j;
            Cz[(long)a * ldC + b] = acc[i][j];
        }
}

// reduce k-split partials -> C, zero diag, accumulate column sums (deg) via atomics (exact ints)
__global__ void reduce_part_deg_kernel(const float* __restrict__ Cpart, float* __restrict__ C,
                                       int ldC, int ksplit, float* __restrict__ deg) {
    int t = blockIdx.x * 256 + threadIdx.x;
    long tot = (long)ldC * ldC;
    if (t >= tot) return;
    float s = 0.f;
    for (int z = 0; z < ksplit; z++) s += Cpart[(long)z * tot + t];
    int a = t / ldC, b = t % ldC;
    if (a == b) s = 0.f;
    C[t] = s;
    if (s != 0.f) atomicAdd(&deg[b], s);
}

// ---------------- K1: colsum partials (optional) || raw msg (no dis scaling) ----------------
template <typename AT>
__global__ void colsum_rawmsg_kernel(const AT* __restrict__ A, int ld, int hascs,
                                     const float* __restrict__ x, const int* __restrict__ perm,
                                     const float* __restrict__ vals, const float* __restrict__ xup,
                                     const int* __restrict__ invp, const float* __restrict__ Wb,
                                     float* __restrict__ degp, float* __restrict__ rm, int n) {
    int nc = hascs ? (ld >> 8) * (ld >> 6) : 0;
    int tid = threadIdx.x;
    if ((int)blockIdx.x < nc) {
        int gx = ld >> 8;
        int bi = blockIdx.x % gx, jb = blockIdx.x / gx;
        int i = bi * 256 + tid;
        int j0 = jb * 64;
        const AT* p = A + (long)j0 * ld + i;
        float s0 = 0.f, s1 = 0.f, s2 = 0.f, s3 = 0.f, s4 = 0.f, s5 = 0.f, s6 = 0.f, s7 = 0.f;
#pragma unroll
        for (int jq = 0; jq < 64; jq += 8) {
            float v[8];
#pragma unroll
            for (int q = 0; q < 8; q++) v[q] = cvtA(p[(long)(jq + q) * ld]);
            s0 += v[0]; s1 += v[1]; s2 += v[2]; s3 += v[3];
            s4 += v[4]; s5 += v[5]; s6 += v[6]; s7 += v[7];
        }
        float s = ((s0 + s1) + (s2 + s3)) + ((s4 + s5) + (s6 + s7));
        degp[(long)jb * ld + i] = s;
    } else {
        int idx = ((int)blockIdx.x - nc) * 256 + tid;
        if (idx >= ld * 32) return;
        int i = idx >> 5, c = idx & 31;
        float v = 0.f;
        if (i < n) {
            int src = perm ? perm[i] : i;
            float vs = vals ? vals[i] : 1.f;
            int ip = invp ? invp[i] : -1;
            float s = 0.f;
#pragma unroll
            for (int q = 0; q < 32; q++) {
                float xv = x[(long)src * 32 + q];
                if (ip >= 0) xv += xup[(long)ip * 32 + q];
                s += xv * Wb[q * 32 + c];
            }
            v = s * vs;
        }
        rm[idx] = v;
    }
}

// ---------------- aggT with inline dis_j scaling ----------------
template <typename AT>
__global__ __launch_bounds__(256) void aggTs_kernel(const AT* __restrict__ A,
                                                    const float* __restrict__ rm,
                                                    const float* __restrict__ degp, int nparts,
                                                    const float* __restrict__ disC,
                                                    float* __restrict__ aggp, int n, int ld, int jchunk) {
    __shared__ float As[64][64];
    __shared__ float Ms[64][32];
    __shared__ float sdisJ[256];
    const int tid = threadIdx.x;
    const int i0 = blockIdx.x * 64;
    const int j0 = blockIdx.y * jchunk;
    for (int j = tid; j < jchunk; j += 256) {
        int jj = j0 + j;
        float d;
        if (nparts) {
            float s = 0.f;
            for (int z = 0; z < nparts; z++) s += degp[(long)z * ld + jj];
            d = 1.f / sqrtf(s + 2.f);
        } else {
            d = disC[jj];
        }
        sdisJ[j] = d;
    }
    __syncthreads();
    const int il = tid & 63;
    const int cg = tid >> 6;
    const int i = i0 + il;
    const int mrow = tid >> 2;
    const int mc = (tid & 3) * 8;
    float acc[8];
#pragma unroll
    for (int q = 0; q < 8; q++) acc[q] = 0.f;
    for (int jb = j0; jb < j0 + jchunk; jb += 64) {
        AT a16[16];
        float m8[8];
#pragma unroll
        for (int q = 0; q < 16; q++) a16[q] = A[(long)(jb + cg + 4 * q) * ld + i0 + il];
#pragma unroll
        for (int q = 0; q < 8; q++) m8[q] = rm[(long)(jb + mrow) * 32 + mc + q];
        __syncthreads();
#pragma unroll
        for (int q = 0; q < 16; q++) As[cg + 4 * q][il] = cvtA(a16[q]);
        float ds = sdisJ[jb - j0 + mrow];
#pragma unroll
        for (int q = 0; q < 8; q++) Ms[mrow][mc + q] = m8[q] * ds;
        __syncthreads();
#pragma unroll
        for (int jl = 0; jl < 64; jl++) {
            float a = As[jl][il];
#pragma unroll
            for (int q = 0; q < 8; q++) acc[q] += a * Ms[jl][cg * 8 + q];
        }
        __syncthreads();
    }
    if (i < n) {
#pragma unroll
        for (int q = 0; q < 8; q++) aggp[(long)blockIdx.y * APSTR + (long)i * 32 + cg * 8 + q] = acc[q];
    }
}

// ---------------- epilogue: partial sum + dis finalize + self term + keys ----------------
__global__ void epi2_kernel(const float* __restrict__ aggp, int jsplit, const float* __restrict__ rm,
                            const float* __restrict__ degp, int nparts, float* __restrict__ disC,
                            int writeDis, int ld, const float* __restrict__ bb,
                            float* __restrict__ out, int n, const float* __restrict__ p, int npow,
                            unsigned long long* __restrict__ keys) {
    __shared__ float psh[32];
    if (p) {
        if (threadIdx.x < 32) psh[threadIdx.x] = p[threadIdx.x];
        __syncthreads();
    }
    int idx = blockIdx.x * 256 + threadIdx.x;
    int tot = (p ? npow : n) * 32;
    if (idx >= tot) return;
    int i = idx >> 5, c = idx & 31;
    float di;
    if (nparts) {
        float s = 0.f;
        for (int z = 0; z < nparts; z++) s += degp[(long)z * ld + i];
        di = 1.f / sqrtf(s + 2.f);
    } else {
        di = disC[i];
    }
    float v = 0.f;
    if (i < n) {
        float s = 0.f;
        for (int z = 0; z < jsplit; z++) s += aggp[(long)z * APSTR + idx];
        v = (s + 2.f * di * rm[idx]) * di + bb[c];
        v = fmaxf(v, 0.f);
        out[idx] = v;
    }
    if (writeDis && c == 0) disC[i] = di;
    if (p) {
        float pc = psh[c];
        float d = v * pc;
        float nq = pc * pc;
#pragma unroll
        for (int st = 16; st >= 1; st >>= 1) {
            d += __shfl_xor(d, st);
            nq += __shfl_xor(nq, st);
        }
        if (c == 0) {
            unsigned long long kk = 0ULL;
            if (i < n) {
                float sc = tanhf(d / sqrtf(nq));
                unsigned u = __float_as_uint(sc);
                u = (u & 0x80000000u) ? ~u : (u | 0x80000000u);
                kk = ((unsigned long long)u << 32) | (unsigned)(~i);
            }
            keys[i] = kk;
        }
    }
}

// level-0 sparse agg + epilogue + level-0 pooling keys (wave-reduced)
__global__ void cscagg_epi_keys_kernel(const int* __restrict__ rowpD, const int* __restrict__ srcs,
                                       const float* __restrict__ msg, const float* __restrict__ dis,
                                       const float* __restrict__ fixb, const float* __restrict__ bb,
                                       float* __restrict__ out, int n, const float* __restrict__ p,
                                       unsigned long long* __restrict__ keys) {
    __shared__ float psh[32];
    if (threadIdx.x < 32) psh[threadIdx.x] = p[threadIdx.x];
    __syncthreads();
    int idx = blockIdx.x * 256 + threadIdx.x;
    if (idx >= n * 32) return;
    int i = idx >> 5, c = idx & 31;
    float acc = 0.f;
    int e0 = rowpD[i], e1 = rowpD[i + 1];
    for (int e = e0; e < e1; e++) acc += msg[(long)srcs[e] * 32 + c];
    float v = (acc + fixb[i] * msg[idx]) * dis[i] + bb[c];
    v = fmaxf(v, 0.f);
    out[idx] = v;
    float pc = psh[c];
    float d = v * pc;
    float nq = pc * pc;
#pragma unroll
    for (int st = 16; st >= 1; st >>= 1) {
        d += __shfl_xor(d, st);
        nq += __shfl_xor(nq, st);
    }
    if (c == 0) {
        float sc = tanhf(d / sqrtf(nq));
        unsigned u = __float_as_uint(sc);
        u = (u & 0x80000000u) ? ~u : (u | 0x80000000u);
        keys[i] = ((unsigned long long)u << 32) | (unsigned)(~i);
    }
}

// final up-level msg (32->3) with fused unpool
__global__ void msg3up_kernel(const float* __restrict__ res, const float* __restrict__ xup,
                              const int* __restrict__ invp, const float* __restrict__ Wb,
                              const float* __restrict__ dis, float* __restrict__ msg, int n) {
    int idx = blockIdx.x * 256 + threadIdx.x;
    if (idx >= n * 3) return;
    int i = idx / 3, c = idx % 3;
    int ip = invp[i];
    float s = 0.f;
#pragma unroll
    for (int q = 0; q < 32; q++) {
        float xv = res[(long)i * 32 + q];
        if (ip >= 0) xv += xup[(long)ip * 32 + q];
        s += xv * Wb[q * 3 + c];
    }
    msg[idx] = s * dis[i];
}

// final sparse GCN epilogue + log_softmax fused, writes d_out directly
__global__ void cscagg_lsm_kernel(const int* __restrict__ rowpD, const int* __restrict__ srcs,
                                  const float* __restrict__ msg, const float* __restrict__ dis,
                                  const float* __restrict__ fixb, const float* __restrict__ bb,
                                  float* __restrict__ out, int n) {
    int i = blockIdx.x * 256 + threadIdx.x;
    if (i >= n) return;
    float a0 = 0.f, a1 = 0.f, a2 = 0.f;
    int e0 = rowpD[i], e1 = rowpD[i + 1];
    for (int e = e0; e < e1; e++) {
        const float* m = &msg[(long)srcs[e] * 3];
        a0 += m[0]; a1 += m[1]; a2 += m[2];
    }
    float di = dis[i], fx = fixb[i];
    float v0 = (a0 + fx * msg[i * 3]) * di + bb[0];
    float v1 = (a1 + fx * msg[i * 3 + 1]) * di + bb[1];
    float v2 = (a2 + fx * msg[i * 3 + 2]) * di + bb[2];
    float m = fmaxf(v0, fmaxf(v1, v2));
    float s = expf(v0 - m) + expf(v1 - m) + expf(v2 - m);
    float l = m + logf(s);
    out[i * 3] = v0 - l;
    out[i * 3 + 1] = v1 - l;
    out[i * 3 + 2] = v2 - l;
}

// standalone top-k rank
__global__ __launch_bounds__(256) void topk_rank_kernel(const unsigned long long* __restrict__ keys,
                                                        int npow, int k, int* __restrict__ perm,
                                                        float* __restrict__ vals,
                                                        int* __restrict__ invperm) {
    __shared__ unsigned long long ks[4096];
    __shared__ int psum[256];
    const int tid = threadIdx.x;
    for (int t = tid; t < npow; t += 256) ks[t] = keys[t];
    __syncthreads();
    const int m = tid & 15;
    const int chunk = tid >> 4;
    const int myi = blockIdx.x * 16 + m;
    unsigned long long my = ks[myi];
    const int cl = npow >> 4;
    const unsigned long long* base = &ks[chunk * cl];
    int r = 0;
#pragma unroll 4
    for (int j = 0; j < cl; j++) r += (base[j] > my) ? 1 : 0;
    psum[chunk * 16 + m] = r;
    __syncthreads();
    if (tid < 16) {
        int mk_i = blockIdx.x * 16 + tid;
        unsigned long long mk = ks[mk_i];
        int rank = 0;
#pragma unroll
        for (int c = 0; c < 16; c++) rank += psum[c * 16 + tid];
        invperm[mk_i] = (rank < k) ? rank : -1;
        if (rank < k) {
            perm[rank] = (int)(~(unsigned)mk);
            unsigned u = (unsigned)(mk >> 32);
            u = (u & 0x80000000u) ? (u ^ 0x80000000u) : ~u;
            vals[rank] = __uint_as_float(u);
        }
    }
}

// ---------------- host ----------------
static void run_dense(hipStream_t st, const void* A, int abf, int n, int ld, const float* x,
                      const int* perm, const float* vals, const float* xup, const int* invp,
                      const float* Wt, const float* bt, float* out,
                      float* degp, int nparts, int hascs, float* disC, int writeDis,
                      float* aggp, float* rm,
                      const float* pnext, int npow, unsigned long long* keys) {
    {
        int nc = hascs ? (ld >> 8) * (ld >> 6) : 0;
        int g = nc + (ld * 32 + 255) / 256;
        if (abf)
            colsum_rawmsg_kernel<unsigned short><<<g, 256, 0, st>>>(
                (const unsigned short*)A, ld, hascs, x, perm, vals, xup, invp, Wt, degp, rm, n);
        else
            colsum_rawmsg_kernel<float><<<g, 256, 0, st>>>(
                (const float*)A, ld, hascs, x, perm, vals, xup, invp, Wt, degp, rm, n);
    }
    int jsplit = (ld >= 256) ? (ld >> 8) : 1;
    if (jsplit < 1) jsplit = 1;
    int jchunk = ld / jsplit;
    dim3 ga(ld / 64, jsplit);
    if (abf)
        aggTs_kernel<unsigned short><<<ga, 256, 0, st>>>((const unsigned short*)A, rm,
                                                         nparts ? degp : nullptr, nparts, disC,
                                                         aggp, n, ld, jchunk);
    else
        aggTs_kernel<float><<<ga, 256, 0, st>>>((const float*)A, rm, nparts ? degp : nullptr,
                                                nparts, disC, aggp, n, ld, jchunk);
    int gme = ((pnext ? npow : n) * 32 + 255) / 256;
    epi2_kernel<<<gme, 256, 0, st>>>(aggp, jsplit, rm, nparts ? degp : nullptr, nparts, disC,
                                     writeDis, ld, bt, out, n, pnext, npow, keys);
}

extern "C" void kernel_launch(void* const* d_in, const int* in_sizes, int n_in,
                              void* d_out, int out_size, void* d_ws, size_t ws_size,
                              hipStream_t stream) {
    const float* x0f = (const float*)d_in[0];
    const int* eidx = (const int*)d_in[1];
    const float* W0f = (const float*)d_in[2];
    const float* b0f = (const float*)d_in[3];
    const float* Wdf = (const float*)d_in[4];
    const float* bdf = (const float*)d_in[5];
    const float* Pf = (const float*)d_in[6];
    const float* Wuf = (const float*)d_in[7];
    const float* buf2 = (const float*)d_in[8];
    const float* Wlf = (const float*)d_in[9];
    const float* blf = (const float*)d_in[10];
    const int E = in_sizes[1] / 2;

    unsigned char* w = (unsigned char*)d_ws;
    size_t off = 0;
    auto alloc = [&](size_t bytes) -> void* {
        void* p = w + off;
        off += (bytes + 255) & ~(size_t)255;
        return p;
    };
    int* rowcnt = (int*)alloc(N0 * 4);
    int* rowcntD = (int*)alloc(N0 * 4);
    int* diagcnt = (int*)alloc(N0 * 4);
    int* rowp = (int*)alloc((N0 + 1) * 4);
    int* rowpD = (int*)alloc((N0 + 1) * 4);
    int* cursor = (int*)alloc(N0 * 4);
    int* cursorD = (int*)alloc(N0 * 4);
    int* cols = (int*)alloc((size_t)EMAX * 4);
    int* srcs = (int*)alloc((size_t)EMAX * 4);
    float* dis0 = (float*)alloc(N0 * 4);
    float* fixb0 = (float*)alloc(N0 * 4);
    unsigned long long* keys = (unsigned long long*)alloc((size_t)N0 * 8);
    unsigned short* A1 = (unsigned short*)alloc((size_t)2048 * 2048 * 2);   // bf16 exact ints
    float* A2 = (float*)alloc((size_t)1024 * 1024 * 4);
    float* A3 = (float*)alloc((size_t)512 * 512 * 4);
    float* A4 = (float*)alloc((size_t)256 * 256 * 4);
    float* Gr = (float*)alloc((size_t)1024 * 2048 * 4);
    float* Gc = (float*)alloc((size_t)2048 * 1024 * 4);
    unsigned short* Grb = (unsigned short*)alloc((size_t)1024 * 2048 * 2);
    unsigned short* GcTb = (unsigned short*)alloc((size_t)1024 * 2048 * 2);
    float* Cpart = (float*)alloc((size_t)8 * 512 * 512 * 4);
    float* degp = (float*)alloc((size_t)32 * 2048 * 4);
    float* aggp = (float*)alloc((size_t)8 * APSTR * 4);
    float* xs0 = (float*)alloc((size_t)N0 * H * 4);
    float* xs1 = (float*)alloc((size_t)2000 * H * 4);
    float* xs2 = (float*)alloc((size_t)1000 * H * 4);
    float* xs3 = (float*)alloc((size_t)500 * H * 4);
    float* xtB = (float*)alloc((size_t)N0 * H * 4);
    float* xtC = (float*)alloc((size_t)N0 * H * 4);
    float* msgb = (float*)alloc((size_t)N0 * H * 4);
    float* disL = (float*)alloc((size_t)4 * N0 * 4);
    int* invpermL = (int*)alloc((size_t)4 * N0 * 4);
    const int ksz[4] = {2000, 1000, 500, 250};
    int* perm[4];
    float* vals[4];
    for (int i = 0; i < 4; i++) perm[i] = (int*)alloc((size_t)ksz[i] * 4);
    for (int i = 0; i < 4; i++) vals[i] = (float*)alloc((size_t)ksz[i] * 4);

    if (off > ws_size) {
        fill_sentinel_kernel<<<(out_size + 255) / 256, 256, 0, stream>>>((float*)d_out, out_size);
        return;
    }

    const int nlvl[5] = {N0, 2000, 1000, 500, 250};
    const int ldl[5] = {N0, 2048, 1024, 512, 256};
    const int npw[4] = {4096, 2048, 1024, 512};
    void* Afp[5] = {nullptr, A1, A2, A3, A4};
    const int abfL[5] = {0, 1, 0, 0, 0};
    float* xsb[4] = {xs0, xs1, xs2, xs3};

    // ---- CSR build + level-0 stats ----
    hipMemsetAsync(rowcnt, 0, (size_t)N0 * 3 * 4, stream);
    build_stats_kernel<<<(E + 255) / 256, 256, 0, stream>>>(eidx, E, rowcnt, rowcntD, diagcnt);
    scan2_kernel<<<1, 1024, 0, stream>>>(rowcnt, rowp, cursor, rowcntD, rowpD, cursorD);
    {
        int nf = (E + 255) / 256;
        int nm = (N0 * H + 255) / 256;
        fillcsr_msg0_kernel<<<nf + nm, 256, 0, stream>>>(eidx, E, cursor, cols, cursorD, srcs,
                                                         x0f, W0f, rowcntD, diagcnt, dis0, fixb0,
                                                         msgb, N0);
    }
    cscagg_epi_keys_kernel<<<(N0 * H + 255) / 256, 256, 0, stream>>>(rowpD, srcs, msgb, dis0, fixb0,
                                                                     b0f, xs0, N0, Pf, keys);
    float* xcur = xs0;

    // ---- down path ----
    for (int i = 0; i < 4; ++i) {
        int kk = ksz[i], ldn = ldl[i + 1];
        topk_rank_kernel<<<npw[i] / 16, 256, 0, stream>>>(keys, npw[i], kk, perm[i], vals[i],
                                                          invpermL + i * N0);
        // ---- build A_{i+1} ----
        if (i == 0) {
            aug0_kernel<<<ldn, 256, 0, stream>>>(rowp, cols, perm[0], invpermL, kk, ldn, A1);
        } else if (i == 1) {
            int ldM = ldl[i];
            int half = (ldM >> 8) * ldn;
            int tseg = (ldM >> 5) * (ldM >> 5);
            int zrow = (((ldn - kk) * ldM) + 255) >> 8;
            int zseg = ((ldn * ldn) / 4 + 255) / 256;
            int dseg = (ldn + 255) / 256;
            gatherAB_bf16_kernel<<<half + tseg + zrow + zseg + dseg, 256, 0, stream>>>(
                A1, ldM, perm[i], invpermL + i * N0, kk, Grb, GcTb, ldn, A2, degp);
            int ksplit = 2;
            int kchunk = ldM / ksplit;
            dim3 gg(ldn / 64, ldn / 64, ksplit);
            mfma_aug_kernel<<<gg, 256, 0, stream>>>(Grb, GcTb, A2, degp, ldM, ldn, kchunk);
        } else {
            int ldM = ldl[i];
            int half = (ldM >> 8) * ldn;
            int tseg = (ldM >> 5) * (ldM >> 5);
            int zrow = (((ldn - kk) * ldM) + 255) >> 8;
            int dseg = (ldn + 255) / 256;
            gatherGT_kernel<<<half + tseg + zrow + dseg, 256, 0, stream>>>(
                (const float*)Afp[i], ldM, perm[i], invpermL + i * N0, kk, Gr, Gc, ldn, degp);
            int ksplit = 8;
            int kchunk = ldM / ksplit;
            dim3 gg(ldn / 64, ldn / 64, ksplit);
            gemm64_kernel<<<gg, 256, 0, stream>>>(Gr, Gc, Cpart, ldM, ldn, kchunk);
            long tot = (long)ldn * ldn;
            reduce_part_deg_kernel<<<(tot + 255) / 256, 256, 0, stream>>>(Cpart, (float*)Afp[i + 1],
                                                                          ldn, ksplit, degp);
        }
        // ---- GCN on level i+1 ----
        float* outx = (i < 3) ? xsb[i + 1] : xtB;
        const float* pnext = (i < 3) ? (Pf + (i + 1) * H) : nullptr;
        int npown = (i < 3) ? npw[i + 1] : 0;
        int hascs = (i == 0) ? 1 : 0;             // levels 2/3/4 get deg fused into A-build
        int nparts = (i == 0) ? (ldn >> 6) : 1;
        run_dense(stream, Afp[i + 1], abfL[i + 1], kk, ldn, xcur, perm[i], vals[i], nullptr,
                  nullptr, Wdf + i * (H * H), bdf + i * H, outx, degp, nparts, hascs,
                  disL + i * N0, (i < 3) ? 1 : 0, aggp, msgb, pnext, npown, keys);
        xcur = outx;
    }

    // ---- up path (dis cached in disL; unpool fused into rawmsg via invperm) ----
    for (int i = 0; i < 4; ++i) {
        int j = 3 - i;
        int nj = nlvl[j];
        if (i < 3) {
            int ldn = ldl[j];
            float* outx = (xcur == xtB) ? xtC : xtB;
            run_dense(stream, Afp[j], abfL[j], nj, ldn, xsb[j], nullptr, nullptr, xcur,
                      invpermL + j * N0, Wuf + i * (H * H), buf2 + i * H, outx, nullptr, 0, 0,
                      disL + (j - 1) * N0, 0, aggp, msgb, nullptr, 0, nullptr);
            xcur = outx;
        } else {
            msg3up_kernel<<<(N0 * 3 + 255) / 256, 256, 0, stream>>>(xs0, xcur, invpermL, Wlf, dis0,
                                                                    msgb, N0);
            cscagg_lsm_kernel<<<(N0 + 255) / 256, 256, 0, stream>>>(rowpD, srcs, msgb, dis0, fixb0,
                                                                    blf, (float*)d_out, N0);
        }
    }
}